// Round 4
// baseline (10822.807 us; speedup 1.0000x reference)
//
#include <hip/hip_runtime.h>
#include <cmath>

// Problem constants (B=1)
#define TS 2048   // sequence length T
#define DM 2048   // model dim D
#define NH 16     // heads
#define DH 128    // head dim
#define FF 5632   // ffn dim
#define TTCH 256  // attention query-chunk rows (32 MB logits chunk)
#define FCH 512   // ffn row-chunk

// ---------------------------------------------------------------------------
// rmsnorm over rows of (rows, 2048), with weight
// ---------------------------------------------------------------------------
__global__ __launch_bounds__(256) void rmsnorm_k(const float* __restrict__ in,
                                                 const float* __restrict__ w,
                                                 float* __restrict__ out) {
  const int row = blockIdx.x;
  const int tid = threadIdx.x;
  const float* r = in + (size_t)row * DM;
  float4 v0 = ((const float4*)r)[tid];
  float4 v1 = ((const float4*)r)[tid + 256];
  float ss = v0.x*v0.x + v0.y*v0.y + v0.z*v0.z + v0.w*v0.w
           + v1.x*v1.x + v1.y*v1.y + v1.z*v1.z + v1.w*v1.w;
  #pragma unroll
  for (int d = 1; d < 64; d <<= 1) ss += __shfl_xor(ss, d);
  __shared__ float red[4];
  if ((tid & 63) == 0) red[tid >> 6] = ss;
  __syncthreads();
  ss = red[0] + red[1] + red[2] + red[3];
  const float sc = rsqrtf(ss * (1.0f / DM) + 1e-6f);
  float4 w0 = ((const float4*)w)[tid];
  float4 w1 = ((const float4*)w)[tid + 256];
  float* po = out + (size_t)row * DM;
  ((float4*)po)[tid]       = make_float4(v0.x*sc*w0.x, v0.y*sc*w0.y, v0.z*sc*w0.z, v0.w*sc*w0.w);
  ((float4*)po)[tid + 256] = make_float4(v1.x*sc*w1.x, v1.y*sc*w1.y, v1.z*sc*w1.z, v1.w*sc*w1.w);
}

// ---------------------------------------------------------------------------
// Tiled fp32 GEMM: C[M,N] = epi(A @ B (+R))
// TB=0: B is (K,N) row-major.  TB=1: B is (N,K) row-major, compute A@B^T.
// EPI: 0 none, 1 gelu(exact), 2 tanh, 3 silu, 4 add residual R
// BM=BN=128, BK=16, 256 threads, 8x8 micro-tile.
// Requires M%128==0, K%16==0, N%4==0 (N guarded).
// ---------------------------------------------------------------------------
template<int TB, int EPI>
__global__ __launch_bounds__(256) void gemm_k(
    const float* __restrict__ A, const float* __restrict__ B,
    float* __restrict__ C, const float* __restrict__ R,
    int M, int N, int K, int lda, int ldb, int ldc,
    long sA, long sB, long sC) {
  const int z = blockIdx.z;
  A += (size_t)z * sA; B += (size_t)z * sB; C += (size_t)z * sC;
  const int n0 = blockIdx.x * 128, m0 = blockIdx.y * 128;
  const int tid = threadIdx.x;
  const int tr = tid >> 4, tc = tid & 15;
  __shared__ float As[16][132];
  __shared__ float Bs[16][132];
  float acc[8][8];
  #pragma unroll
  for (int i = 0; i < 8; ++i)
    #pragma unroll
    for (int j = 0; j < 8; ++j) acc[i][j] = 0.f;

  for (int k0 = 0; k0 < K; k0 += 16) {
    #pragma unroll
    for (int l = 0; l < 2; ++l) {
      int fi = tid + l * 256;
      int row = fi >> 2, kq = fi & 3;
      float4 av = *(const float4*)&A[(size_t)(m0 + row) * lda + k0 + kq * 4];
      As[kq*4+0][row] = av.x; As[kq*4+1][row] = av.y;
      As[kq*4+2][row] = av.z; As[kq*4+3][row] = av.w;
    }
    if (TB == 0) {
      #pragma unroll
      for (int l = 0; l < 2; ++l) {
        int fi = tid + l * 256;
        int kr = fi >> 5, cq = fi & 31;
        int gc = n0 + cq * 4;
        float4 bv = make_float4(0.f, 0.f, 0.f, 0.f);
        if (gc < N) bv = *(const float4*)&B[(size_t)(k0 + kr) * ldb + gc];
        *(float4*)&Bs[kr][cq * 4] = bv;
      }
    } else {
      #pragma unroll
      for (int l = 0; l < 2; ++l) {
        int fi = tid + l * 256;
        int col = fi >> 2, kq = fi & 3;
        int gc = n0 + col;
        float4 bv = make_float4(0.f, 0.f, 0.f, 0.f);
        if (gc < N) bv = *(const float4*)&B[(size_t)gc * ldb + k0 + kq * 4];
        Bs[kq*4+0][col] = bv.x; Bs[kq*4+1][col] = bv.y;
        Bs[kq*4+2][col] = bv.z; Bs[kq*4+3][col] = bv.w;
      }
    }
    __syncthreads();
    #pragma unroll
    for (int kk = 0; kk < 16; ++kk) {
      float a[8], b[8];
      *(float4*)&a[0] = *(const float4*)&As[kk][tr * 8];
      *(float4*)&a[4] = *(const float4*)&As[kk][tr * 8 + 4];
      *(float4*)&b[0] = *(const float4*)&Bs[kk][tc * 4];
      *(float4*)&b[4] = *(const float4*)&Bs[kk][64 + tc * 4];
      #pragma unroll
      for (int i = 0; i < 8; ++i)
        #pragma unroll
        for (int j = 0; j < 8; ++j)
          acc[i][j] = fmaf(a[i], b[j], acc[i][j]);
    }
    __syncthreads();
  }

  #pragma unroll
  for (int i = 0; i < 8; ++i) {
    int gr = m0 + tr * 8 + i;
    #pragma unroll
    for (int half = 0; half < 2; ++half) {
      int gc = n0 + half * 64 + tc * 4;
      if (gc < N) {
        float v[4];
        #pragma unroll
        for (int j = 0; j < 4; ++j) {
          float t = acc[i][half * 4 + j];
          if (EPI == 1)      t = 0.5f * t * (1.0f + erff(t * 0.70710678118654752f));
          else if (EPI == 2) t = tanhf(t);
          else if (EPI == 3) t = t / (1.0f + expf(-t));
          v[j] = t;
        }
        if (EPI == 4) {
          float4 rv = *(const float4*)&R[(size_t)gr * ldc + gc];
          v[0] += rv.x; v[1] += rv.y; v[2] += rv.z; v[3] += rv.w;
        }
        *(float4*)&C[(size_t)gr * ldc + gc] = make_float4(v[0], v[1], v[2], v[3]);
      }
    }
  }
}

// ---------------------------------------------------------------------------
// Per-(t, head) IN PLACE in qkv (T, 3D): rmsnorm(q), rmsnorm(k), RoPE both,
// scale q by Dh^-0.5.  v untouched.  64 threads = 1 wave; lane i holds the
// RoPE pair (x1[i], x2[i]) = elems (i, i+64) of the head row.
// ---------------------------------------------------------------------------
__global__ __launch_bounds__(64) void qkrope_k(float* __restrict__ qkv,
                                               const float* __restrict__ qnw,
                                               const float* __restrict__ knw) {
  const int n = blockIdx.x, t = blockIdx.y, i = threadIdx.x;
  float* row = qkv + (size_t)t * (3 * DM) + n * DH;
  float q1 = row[i],      q2 = row[i + 64];
  float k1 = row[DM + i], k2 = row[DM + i + 64];
  float ssq = q1 * q1 + q2 * q2;
  float ssk = k1 * k1 + k2 * k2;
  #pragma unroll
  for (int d = 1; d < 64; d <<= 1) {
    ssq += __shfl_xor(ssq, d);
    ssk += __shfl_xor(ssk, d);
  }
  const float rq = rsqrtf(ssq * (1.0f / DH) + 1e-6f);
  const float rk = rsqrtf(ssk * (1.0f / DH) + 1e-6f);
  float qn1 = q1 * rq * qnw[i], qn2 = q2 * rq * qnw[i + 64];
  float kn1 = k1 * rk * knw[i], kn2 = k2 * rk * knw[i + 64];
  float inv = 1.0f / powf(10000.0f, (float)i * (1.0f / 64.0f));
  float ang = (float)t * inv;
  float c = (float)cos((double)ang);
  float s = (float)sin((double)ang);
  const float scale = 0.08838834764831845f;  // 128^-0.5 (q only)
  row[i]           = (qn1 * c - qn2 * s) * scale;
  row[i + 64]      = (qn2 * c + qn1 * s) * scale;
  row[DM + i]      = kn1 * c - kn2 * s;
  row[DM + i + 64] = kn2 * c + kn1 * s;
}

// ---------------------------------------------------------------------------
// dyn-w: w[t,c,i,n] = sum_kk dwh[t,c,kk]*qkw[c,kk,i,n]; rmsnorm_noscale over
// n (16) for i<2.  One block per t; wave c; 16-lane groups share (c,i).
// ---------------------------------------------------------------------------
__global__ __launch_bounds__(256) void dynw_k(const float* __restrict__ dwh,
                                              const float* __restrict__ qkw,
                                              float* __restrict__ dynw) {
  const int t = blockIdx.x, tid = threadIdx.x;
  __shared__ float dwhs[256];
  dwhs[tid] = dwh[(size_t)t * 256 + tid];
  __syncthreads();
  const int c = tid >> 6, r = tid & 63, ifull = r >> 4, n = r & 15;
  const float* qp = qkw + (size_t)(c * 64) * 64 + ifull * 16 + n;
  const float* dp = dwhs + c * 64;
  float acc = 0.f;
  #pragma unroll 8
  for (int kk = 0; kk < 64; ++kk) acc = fmaf(dp[kk], qp[(size_t)kk * 64], acc);
  float ss = acc * acc;
  #pragma unroll
  for (int m = 1; m < 16; m <<= 1) ss += __shfl_xor(ss, m);
  float v = (ifull < 2) ? acc * rsqrtf(ss * (1.0f / 16) + 1e-6f) : acc;
  dynw[(size_t)t * 256 + tid] = v;
}

// ---------------------------------------------------------------------------
// cross_head_proj, in place on a logits CHUNK x (NH, TTCH, TS).
// One thread per (tloc, s), all 16 heads.  t0 = global row offset of chunk.
// ---------------------------------------------------------------------------
__global__ __launch_bounds__(256) void chp_k(float* __restrict__ x,
                                             const float* __restrict__ dynw,
                                             const float* __restrict__ ddv,
                                             int cq, int ck, int oq, int ok,
                                             int t0) {
  const int tl = blockIdx.y;
  const int tg = t0 + tl;
  const int s = blockIdx.x * 256 + threadIdx.x;
  const int tid = threadIdx.x;
  __shared__ float qw[64];   // [i*16+n] i=0..3 (0,1=w1n; 2,3=w2)
  __shared__ float qdds[16];
  if (tid < 64) qw[tid] = dynw[(size_t)tg * 256 + cq * 64 + tid];
  else if (tid < 80) qdds[tid - 64] = ddv[(size_t)tg * 64 + oq + (tid - 64)];
  __syncthreads();
  const size_t plane = (size_t)TTCH * TS;
  float* p = x + (size_t)tl * TS + s;
  float xv[16];
  #pragma unroll
  for (int n = 0; n < 16; ++n) xv[n] = p[n * plane];
  float qh0 = 0.f, qh1 = 0.f, kh0 = 0.f, kh1 = 0.f;
  const float* kwp = dynw + (size_t)s * 256 + ck * 64;
  #pragma unroll
  for (int n = 0; n < 16; ++n) {
    qh0 = fmaf(xv[n], qw[n], qh0);
    qh1 = fmaf(xv[n], qw[16 + n], qh1);
    kh0 = fmaf(xv[n], kwp[n], kh0);
    kh1 = fmaf(xv[n], kwp[16 + n], kh1);
  }
  const float* kddp = ddv + (size_t)s * 64 + ok;
  #pragma unroll
  for (int n = 0; n < 16; ++n) {
    float r = xv[n]
            + qh0 * qw[32 + n] + qh1 * qw[48 + n]
            + kh0 * kwp[32 + n] + kh1 * kwp[48 + n]
            + xv[n] * (qdds[n] + kddp[n]);
    p[n * plane] = r;
  }
}

// ---------------------------------------------------------------------------
// causal softmax in place on chunk (NH, TTCH, TS).  Block per (tloc, n).
// masked (s > t0+tloc) -> 0.
// ---------------------------------------------------------------------------
__global__ __launch_bounds__(256) void softmax_k(float* __restrict__ x, int t0) {
  const int tl = blockIdx.x, n = blockIdx.y, tid = threadIdx.x;
  const int tg = t0 + tl;
  float* row = x + ((size_t)n * TTCH + tl) * TS;
  float l[8];
  float m = -INFINITY;
  #pragma unroll
  for (int k = 0; k < 8; ++k) {
    int s = tid + k * 256;
    l[k] = (s <= tg) ? row[s] : -INFINITY;
    m = fmaxf(m, l[k]);
  }
  #pragma unroll
  for (int d = 1; d < 64; d <<= 1) m = fmaxf(m, __shfl_xor(m, d));
  __shared__ float red[4];
  if ((tid & 63) == 0) red[tid >> 6] = m;
  __syncthreads();
  m = fmaxf(fmaxf(red[0], red[1]), fmaxf(red[2], red[3]));
  float sum = 0.f;
  #pragma unroll
  for (int k = 0; k < 8; ++k) {
    int s = tid + k * 256;
    l[k] = (s <= tg) ? expf(l[k] - m) : 0.f;
    sum += l[k];
  }
  #pragma unroll
  for (int d = 1; d < 64; d <<= 1) sum += __shfl_xor(sum, d);
  __syncthreads();
  if ((tid & 63) == 0) red[tid >> 6] = sum;
  __syncthreads();
  sum = red[0] + red[1] + red[2] + red[3];
  const float isum = 1.0f / sum;
  #pragma unroll
  for (int k = 0; k < 8; ++k) row[tid + k * 256] = l[k] * isum;
}

// a *= b, float4 grid-stride
__global__ __launch_bounds__(256) void mul_k(float* __restrict__ a,
                                             const float* __restrict__ b,
                                             long n4) {
  long i = (long)blockIdx.x * 256 + threadIdx.x;
  const long stride = (long)gridDim.x * 256;
  for (; i < n4; i += stride) {
    float4 av = ((const float4*)a)[i];
    float4 bv = ((const float4*)b)[i];
    ((float4*)a)[i] = make_float4(av.x * bv.x, av.y * bv.y, av.z * bv.z, av.w * bv.w);
  }
}

// ---------------------------------------------------------------------------
extern "C" void kernel_launch(void* const* d_in, const int* in_sizes, int n_in,
                              void* d_out, int out_size, void* d_ws, size_t ws_size,
                              hipStream_t stream) {
  (void)in_sizes; (void)n_in; (void)out_size; (void)ws_size;
  const float* x    = (const float*)d_in[0];
  const float* anw  = (const float*)d_in[1];
  const float* wqkv = (const float*)d_in[2];
  const float* qnw  = (const float*)d_in[3];
  const float* knw  = (const float*)d_in[4];
  const float* dw1  = (const float*)d_in[5];
  const float* qkw  = (const float*)d_in[6];
  const float* dd   = (const float*)d_in[7];
  const float* wo   = (const float*)d_in[8];
  const float* fnw  = (const float*)d_in[9];
  const float* w1f  = (const float*)d_in[10];
  const float* w3f  = (const float*)d_in[11];
  const float* w2f  = (const float*)d_in[12];
  float* out = (float*)d_out;
  float* ws = (float*)d_ws;

  // Workspace layout (floats).  High-water: 25.2M floats = 101 MB.
  const size_t SZ_D2 = (size_t)TS * DM;            // 4 M floats
  float* hn    = ws;                               // [0,4M)      (T, D)
  float* qkvb  = hn + SZ_D2;                       // [4M,16M)    (T, 3D); q/k roped in place
  float* dwh   = qkvb + (size_t)TS * 3 * DM;       // (T, 256)
  float* dynw  = dwh + (size_t)TS * 256;           // (T, 4,4,16)
  float* ddv   = dynw + (size_t)TS * 256;          // (T, 64)
  float* logc  = ddv + (size_t)TS * 64;            // (NH, TTCH, TS) 32 MB
  // Phase B (post-attention) — aliases dead Phase-A buffers:
  float* ob    = hn;                               // (T, D)  [hn dead after attn]
  float* hb    = qkvb;                             // (T, D)  [qkv dead]
  float* fnb   = qkvb + SZ_D2;                     // (T, D)
  float* g1c   = qkvb + 2 * SZ_D2;                 // (FCH, FF) chunk
  float* g3c   = g1c + (size_t)FCH * FF;           // (FCH, FF) chunk

  const int  ld3 = 3 * DM;                 // row stride inside qkv
  const long sLG = (long)TTCH * TS;        // per-head logits-chunk stride
  const float* qp = qkvb;                  // head n at qp + n*DH, lda=3D
  const float* kp = qkvb + DM;
  const float* vp = qkvb + 2 * DM;

  // 1. hn = rmsnorm(x, attn_norm_w)
  rmsnorm_k<<<TS, 256, 0, stream>>>(x, anw, hn);
  // 2. qkv = hn @ wqkv
  gemm_k<0,0><<<dim3(48, 16, 1), 256, 0, stream>>>(hn, wqkv, qkvb, nullptr,
      TS, 3*DM, DM, DM, 3*DM, 3*DM, 0, 0, 0);
  // 3. dyn-w pieces from hn
  gemm_k<0,1><<<dim3(2, 16, 1), 256, 0, stream>>>(hn, dw1, dwh, nullptr,
      TS, 256, DM, DM, 256, 256, 0, 0, 0);                 // gelu(hn@dw1)
  gemm_k<0,2><<<dim3(1, 16, 1), 256, 0, stream>>>(hn, dd, ddv, nullptr,
      TS, 64, DM, DM, 64, 64, 0, 0, 0);                    // tanh(hn@dd)
  dynw_k<<<TS, 256, 0, stream>>>(dwh, qkw, dynw);
  // 4. q/k: rmsnorm + rope + q-scale, in place in qkvb
  qkrope_k<<<dim3(NH, TS), 64, 0, stream>>>(qkvb, qnw, knw);
  // 5-9. attention in query chunks of TTCH rows (32 MB scratch)
  for (int t0 = 0; t0 < TS; t0 += TTCH) {
    // logits chunk = q[t0:t0+TTCH] @ k^T   (batched over heads via sA=sB=DH)
    gemm_k<1,0><<<dim3(16, TTCH/128, NH), 256, 0, stream>>>(
        qp + (size_t)t0 * ld3, kp, logc, nullptr,
        TTCH, TS, DH, ld3, ld3, TS, DH, DH, sLG);
    // cross_head_proj (pre), in place
    chp_k<<<dim3(8, TTCH), 256, 0, stream>>>(logc, dynw, ddv, 0, 1, 0, 16, t0);
    // causal softmax, in place (masked entries -> exactly 0)
    softmax_k<<<dim3(TTCH, NH), 256, 0, stream>>>(logc, t0);
    // cross_head_proj (post), in place (zero columns stay zero)
    chp_k<<<dim3(8, TTCH), 256, 0, stream>>>(logc, dynw, ddv, 2, 3, 32, 48, t0);
    // o chunk = probs @ v  -> (T, D), head n occupies cols [n*DH, (n+1)*DH)
    gemm_k<0,0><<<dim3(1, TTCH/128, NH), 256, 0, stream>>>(
        logc, vp, ob + (size_t)t0 * DM, nullptr,
        TTCH, DH, TS, TS, ld3, DM, sLG, DH, (long)DH);
  }
  // 10. h = x + o @ wo
  gemm_k<0,4><<<dim3(16, 16, 1), 256, 0, stream>>>(ob, wo, hb, x,
      TS, DM, DM, DM, DM, DM, 0, 0, 0);
  // 11. fn = rmsnorm(h, ffn_norm_w)
  rmsnorm_k<<<TS, 256, 0, stream>>>(hb, fnw, fnb);
  // 12-13. FFN in row chunks of FCH:
  //   g1 = silu(fn@w1f); g3 = fn@w3f; out = h + (g1*g3)@w2f
  for (int r0 = 0; r0 < TS; r0 += FCH) {
    const float* fr = fnb + (size_t)r0 * DM;
    gemm_k<0,3><<<dim3(44, FCH/128, 1), 256, 0, stream>>>(fr, w1f, g1c, nullptr,
        FCH, FF, DM, DM, FF, FF, 0, 0, 0);
    gemm_k<0,0><<<dim3(44, FCH/128, 1), 256, 0, stream>>>(fr, w3f, g3c, nullptr,
        FCH, FF, DM, DM, FF, FF, 0, 0, 0);
    mul_k<<<1024, 256, 0, stream>>>(g1c, g3c, (long)FCH * FF / 4);
    gemm_k<0,4><<<dim3(16, FCH/128, 1), 256, 0, stream>>>(g1c, w2f,
        out + (size_t)r0 * DM, hb + (size_t)r0 * DM,
        FCH, DM, FF, FF, DM, DM, 0, 0, 0);
  }
}

// Round 5
// 5798.439 us; speedup vs baseline: 1.8665x; 1.8665x over previous
//
#include <hip/hip_runtime.h>
#include <cmath>

// Problem constants (B=1)
#define TS 2048   // sequence length T
#define DM 2048   // model dim D
#define NH 16     // heads
#define DH 128    // head dim
#define FF 5632   // ffn dim
#define TTCH 256  // attention query-chunk rows (32 MB logits chunk)
#define FCH 1024  // ffn row-chunk

// ---------------------------------------------------------------------------
// rmsnorm over rows of (rows, 2048), with weight
// ---------------------------------------------------------------------------
__global__ __launch_bounds__(256) void rmsnorm_k(const float* __restrict__ in,
                                                 const float* __restrict__ w,
                                                 float* __restrict__ out) {
  const int row = blockIdx.x;
  const int tid = threadIdx.x;
  const float* r = in + (size_t)row * DM;
  float4 v0 = ((const float4*)r)[tid];
  float4 v1 = ((const float4*)r)[tid + 256];
  float ss = v0.x*v0.x + v0.y*v0.y + v0.z*v0.z + v0.w*v0.w
           + v1.x*v1.x + v1.y*v1.y + v1.z*v1.z + v1.w*v1.w;
  #pragma unroll
  for (int d = 1; d < 64; d <<= 1) ss += __shfl_xor(ss, d);
  __shared__ float red[4];
  if ((tid & 63) == 0) red[tid >> 6] = ss;
  __syncthreads();
  ss = red[0] + red[1] + red[2] + red[3];
  const float sc = rsqrtf(ss * (1.0f / DM) + 1e-6f);
  float4 w0 = ((const float4*)w)[tid];
  float4 w1 = ((const float4*)w)[tid + 256];
  float* po = out + (size_t)row * DM;
  ((float4*)po)[tid]       = make_float4(v0.x*sc*w0.x, v0.y*sc*w0.y, v0.z*sc*w0.z, v0.w*sc*w0.w);
  ((float4*)po)[tid + 256] = make_float4(v1.x*sc*w1.x, v1.y*sc*w1.y, v1.z*sc*w1.z, v1.w*sc*w1.w);
}

// ---------------------------------------------------------------------------
// Tiled fp32 GEMM: C[M,N] = epi(A @ B (+R))
// TB=0: B is (K,N) row-major.  TB=1: B is (N,K) row-major, compute A@B^T.
// EPI: 0 none, 1 gelu(exact), 2 tanh, 3 silu, 4 add residual R
// BM=BN=128, BK=16, 256 threads, 8x8 micro-tile.
// ---------------------------------------------------------------------------
template<int TB, int EPI>
__global__ __launch_bounds__(256) void gemm_k(
    const float* __restrict__ A, const float* __restrict__ B,
    float* __restrict__ C, const float* __restrict__ R,
    int M, int N, int K, int lda, int ldb, int ldc,
    long sA, long sB, long sC) {
  const int z = blockIdx.z;
  A += (size_t)z * sA; B += (size_t)z * sB; C += (size_t)z * sC;
  const int n0 = blockIdx.x * 128, m0 = blockIdx.y * 128;
  const int tid = threadIdx.x;
  const int tr = tid >> 4, tc = tid & 15;
  __shared__ float As[16][132];
  __shared__ float Bs[16][132];
  float acc[8][8];
  #pragma unroll
  for (int i = 0; i < 8; ++i)
    #pragma unroll
    for (int j = 0; j < 8; ++j) acc[i][j] = 0.f;

  for (int k0 = 0; k0 < K; k0 += 16) {
    #pragma unroll
    for (int l = 0; l < 2; ++l) {
      int fi = tid + l * 256;
      int row = fi >> 2, kq = fi & 3;
      float4 av = *(const float4*)&A[(size_t)(m0 + row) * lda + k0 + kq * 4];
      As[kq*4+0][row] = av.x; As[kq*4+1][row] = av.y;
      As[kq*4+2][row] = av.z; As[kq*4+3][row] = av.w;
    }
    if (TB == 0) {
      #pragma unroll
      for (int l = 0; l < 2; ++l) {
        int fi = tid + l * 256;
        int kr = fi >> 5, cq = fi & 31;
        int gc = n0 + cq * 4;
        float4 bv = make_float4(0.f, 0.f, 0.f, 0.f);
        if (gc < N) bv = *(const float4*)&B[(size_t)(k0 + kr) * ldb + gc];
        *(float4*)&Bs[kr][cq * 4] = bv;
      }
    } else {
      #pragma unroll
      for (int l = 0; l < 2; ++l) {
        int fi = tid + l * 256;
        int col = fi >> 2, kq = fi & 3;
        int gc = n0 + col;
        float4 bv = make_float4(0.f, 0.f, 0.f, 0.f);
        if (gc < N) bv = *(const float4*)&B[(size_t)gc * ldb + k0 + kq * 4];
        Bs[kq*4+0][col] = bv.x; Bs[kq*4+1][col] = bv.y;
        Bs[kq*4+2][col] = bv.z; Bs[kq*4+3][col] = bv.w;
      }
    }
    __syncthreads();
    #pragma unroll
    for (int kk = 0; kk < 16; ++kk) {
      float a[8], b[8];
      *(float4*)&a[0] = *(const float4*)&As[kk][tr * 8];
      *(float4*)&a[4] = *(const float4*)&As[kk][tr * 8 + 4];
      *(float4*)&b[0] = *(const float4*)&Bs[kk][tc * 4];
      *(float4*)&b[4] = *(const float4*)&Bs[kk][64 + tc * 4];
      #pragma unroll
      for (int i = 0; i < 8; ++i)
        #pragma unroll
        for (int j = 0; j < 8; ++j)
          acc[i][j] = fmaf(a[i], b[j], acc[i][j]);
    }
    __syncthreads();
  }

  #pragma unroll
  for (int i = 0; i < 8; ++i) {
    int gr = m0 + tr * 8 + i;
    #pragma unroll
    for (int half = 0; half < 2; ++half) {
      int gc = n0 + half * 64 + tc * 4;
      if (gc < N) {
        float v[4];
        #pragma unroll
        for (int j = 0; j < 4; ++j) {
          float t = acc[i][half * 4 + j];
          if (EPI == 1)      t = 0.5f * t * (1.0f + erff(t * 0.70710678118654752f));
          else if (EPI == 2) t = tanhf(t);
          else if (EPI == 3) t = t / (1.0f + expf(-t));
          v[j] = t;
        }
        if (EPI == 4) {
          float4 rv = *(const float4*)&R[(size_t)gr * ldc + gc];
          v[0] += rv.x; v[1] += rv.y; v[2] += rv.z; v[3] += rv.w;
        }
        *(float4*)&C[(size_t)gr * ldc + gc] = make_float4(v[0], v[1], v[2], v[3]);
      }
    }
  }
}

// ---------------------------------------------------------------------------
// Split-K fp32 GEMM partial: P = A[krange] @ B[krange]   (TB=0 layout)
// grid.z = batch * NS + split.  A k-cols offset sp*Kps; B k-rows offset.
// P += sp*sCsp + batch*cColb;  raw accumulation written (epilogue in reduce).
// ---------------------------------------------------------------------------
__global__ __launch_bounds__(256) void gemm_splitk(
    const float* __restrict__ A, const float* __restrict__ B,
    float* __restrict__ P,
    int M, int N, int Kps, int lda, int ldb, int ldc,
    long sAb, long sBb, long cColb, long sCsp, int NS) {
  const int bt = blockIdx.z / NS, sp = blockIdx.z % NS;
  A += (size_t)bt * sAb + (size_t)sp * Kps;
  B += (size_t)bt * sBb + (size_t)sp * Kps * ldb;
  P += (size_t)sp * sCsp + (size_t)bt * cColb;
  const int n0 = blockIdx.x * 128, m0 = blockIdx.y * 128;
  const int tid = threadIdx.x;
  const int tr = tid >> 4, tc = tid & 15;
  __shared__ float As[16][132];
  __shared__ float Bs[16][132];
  float acc[8][8];
  #pragma unroll
  for (int i = 0; i < 8; ++i)
    #pragma unroll
    for (int j = 0; j < 8; ++j) acc[i][j] = 0.f;

  for (int k0 = 0; k0 < Kps; k0 += 16) {
    #pragma unroll
    for (int l = 0; l < 2; ++l) {
      int fi = tid + l * 256;
      int row = fi >> 2, kq = fi & 3;
      float4 av = *(const float4*)&A[(size_t)(m0 + row) * lda + k0 + kq * 4];
      As[kq*4+0][row] = av.x; As[kq*4+1][row] = av.y;
      As[kq*4+2][row] = av.z; As[kq*4+3][row] = av.w;
    }
    #pragma unroll
    for (int l = 0; l < 2; ++l) {
      int fi = tid + l * 256;
      int kr = fi >> 5, cq = fi & 31;
      int gc = n0 + cq * 4;
      float4 bv = make_float4(0.f, 0.f, 0.f, 0.f);
      if (gc < N) bv = *(const float4*)&B[(size_t)(k0 + kr) * ldb + gc];
      *(float4*)&Bs[kr][cq * 4] = bv;
    }
    __syncthreads();
    #pragma unroll
    for (int kk = 0; kk < 16; ++kk) {
      float a[8], b[8];
      *(float4*)&a[0] = *(const float4*)&As[kk][tr * 8];
      *(float4*)&a[4] = *(const float4*)&As[kk][tr * 8 + 4];
      *(float4*)&b[0] = *(const float4*)&Bs[kk][tc * 4];
      *(float4*)&b[4] = *(const float4*)&Bs[kk][64 + tc * 4];
      #pragma unroll
      for (int i = 0; i < 8; ++i)
        #pragma unroll
        for (int j = 0; j < 8; ++j)
          acc[i][j] = fmaf(a[i], b[j], acc[i][j]);
    }
    __syncthreads();
  }

  #pragma unroll
  for (int i = 0; i < 8; ++i) {
    int gr = m0 + tr * 8 + i;
    #pragma unroll
    for (int half = 0; half < 2; ++half) {
      int gc = n0 + half * 64 + tc * 4;
      if (gc < N)
        *(float4*)&P[(size_t)gr * ldc + gc] =
            make_float4(acc[i][half*4], acc[i][half*4+1],
                        acc[i][half*4+2], acc[i][half*4+3]);
    }
  }
}

// ---------------------------------------------------------------------------
// reduce NS split partials (float4 elements), apply epilogue.
// EPI: 0 none, 1 gelu(exact), 2 tanh
// ---------------------------------------------------------------------------
template<int EPI>
__global__ __launch_bounds__(256) void reduce_k(const float* __restrict__ P,
                                                float* __restrict__ out,
                                                long n4, long sSp4, int NS) {
  long i = (long)blockIdx.x * 256 + threadIdx.x;
  const long stride = (long)gridDim.x * 256;
  for (; i < n4; i += stride) {
    float4 s = ((const float4*)P)[i];
    for (int sp = 1; sp < NS; ++sp) {
      float4 v = ((const float4*)P)[i + sp * sSp4];
      s.x += v.x; s.y += v.y; s.z += v.z; s.w += v.w;
    }
    if (EPI == 1) {
      s.x = 0.5f*s.x*(1.0f+erff(s.x*0.70710678118654752f));
      s.y = 0.5f*s.y*(1.0f+erff(s.y*0.70710678118654752f));
      s.z = 0.5f*s.z*(1.0f+erff(s.z*0.70710678118654752f));
      s.w = 0.5f*s.w*(1.0f+erff(s.w*0.70710678118654752f));
    } else if (EPI == 2) {
      s.x = tanhf(s.x); s.y = tanhf(s.y); s.z = tanhf(s.z); s.w = tanhf(s.w);
    }
    ((float4*)out)[i] = s;
  }
}

// ---------------------------------------------------------------------------
// Per-(t, head) IN PLACE in qkv (T, 3D): rmsnorm(q), rmsnorm(k), RoPE both,
// scale q by Dh^-0.5.  v untouched.  64 threads = 1 wave; lane i holds the
// RoPE pair (x1[i], x2[i]) = elems (i, i+64) of the head row.
// ---------------------------------------------------------------------------
__global__ __launch_bounds__(64) void qkrope_k(float* __restrict__ qkv,
                                               const float* __restrict__ qnw,
                                               const float* __restrict__ knw) {
  const int n = blockIdx.x, t = blockIdx.y, i = threadIdx.x;
  float* row = qkv + (size_t)t * (3 * DM) + n * DH;
  float q1 = row[i],      q2 = row[i + 64];
  float k1 = row[DM + i], k2 = row[DM + i + 64];
  float ssq = q1 * q1 + q2 * q2;
  float ssk = k1 * k1 + k2 * k2;
  #pragma unroll
  for (int d = 1; d < 64; d <<= 1) {
    ssq += __shfl_xor(ssq, d);
    ssk += __shfl_xor(ssk, d);
  }
  const float rq = rsqrtf(ssq * (1.0f / DH) + 1e-6f);
  const float rk = rsqrtf(ssk * (1.0f / DH) + 1e-6f);
  float qn1 = q1 * rq * qnw[i], qn2 = q2 * rq * qnw[i + 64];
  float kn1 = k1 * rk * knw[i], kn2 = k2 * rk * knw[i + 64];
  float inv = 1.0f / powf(10000.0f, (float)i * (1.0f / 64.0f));
  float ang = (float)t * inv;
  float c = (float)cos((double)ang);
  float s = (float)sin((double)ang);
  const float scale = 0.08838834764831845f;  // 128^-0.5 (q only)
  row[i]           = (qn1 * c - qn2 * s) * scale;
  row[i + 64]      = (qn2 * c + qn1 * s) * scale;
  row[DM + i]      = kn1 * c - kn2 * s;
  row[DM + i + 64] = kn2 * c + kn1 * s;
}

// ---------------------------------------------------------------------------
// dyn-w: w[t,c,i,n] = sum_kk dwh[t,c,kk]*qkw[c,kk,i,n]; rmsnorm_noscale over
// n (16) for i<2.  One block per t; wave c; 16-lane groups share (c,i).
// ---------------------------------------------------------------------------
__global__ __launch_bounds__(256) void dynw_k(const float* __restrict__ dwh,
                                              const float* __restrict__ qkw,
                                              float* __restrict__ dynw) {
  const int t = blockIdx.x, tid = threadIdx.x;
  __shared__ float dwhs[256];
  dwhs[tid] = dwh[(size_t)t * 256 + tid];
  __syncthreads();
  const int c = tid >> 6, r = tid & 63, ifull = r >> 4, n = r & 15;
  const float* qp = qkw + (size_t)(c * 64) * 64 + ifull * 16 + n;
  const float* dp = dwhs + c * 64;
  float acc = 0.f;
  #pragma unroll 8
  for (int kk = 0; kk < 64; ++kk) acc = fmaf(dp[kk], qp[(size_t)kk * 64], acc);
  float ss = acc * acc;
  #pragma unroll
  for (int m = 1; m < 16; m <<= 1) ss += __shfl_xor(ss, m);
  float v = (ifull < 2) ? acc * rsqrtf(ss * (1.0f / 16) + 1e-6f) : acc;
  dynw[(size_t)t * 256 + tid] = v;
}

// ---------------------------------------------------------------------------
// cross_head_proj, in place on a logits CHUNK x (NH, TTCH, TS).
// One thread per (tloc, s), all 16 heads.  t0 = global row offset of chunk.
// ---------------------------------------------------------------------------
__global__ __launch_bounds__(256) void chp_k(float* __restrict__ x,
                                             const float* __restrict__ dynw,
                                             const float* __restrict__ ddv,
                                             int cq, int ck, int oq, int ok,
                                             int t0) {
  const int tl = blockIdx.y;
  const int tg = t0 + tl;
  const int s = blockIdx.x * 256 + threadIdx.x;
  const int tid = threadIdx.x;
  __shared__ float qw[64];   // [i*16+n] i=0..3 (0,1=w1n; 2,3=w2)
  __shared__ float qdds[16];
  if (tid < 64) qw[tid] = dynw[(size_t)tg * 256 + cq * 64 + tid];
  else if (tid < 80) qdds[tid - 64] = ddv[(size_t)tg * 64 + oq + (tid - 64)];
  __syncthreads();
  const size_t plane = (size_t)TTCH * TS;
  float* p = x + (size_t)tl * TS + s;
  float xv[16];
  #pragma unroll
  for (int n = 0; n < 16; ++n) xv[n] = p[n * plane];
  float qh0 = 0.f, qh1 = 0.f, kh0 = 0.f, kh1 = 0.f;
  const float* kwp = dynw + (size_t)s * 256 + ck * 64;
  #pragma unroll
  for (int n = 0; n < 16; ++n) {
    qh0 = fmaf(xv[n], qw[n], qh0);
    qh1 = fmaf(xv[n], qw[16 + n], qh1);
    kh0 = fmaf(xv[n], kwp[n], kh0);
    kh1 = fmaf(xv[n], kwp[16 + n], kh1);
  }
  const float* kddp = ddv + (size_t)s * 64 + ok;
  #pragma unroll
  for (int n = 0; n < 16; ++n) {
    float r = xv[n]
            + qh0 * qw[32 + n] + qh1 * qw[48 + n]
            + kh0 * kwp[32 + n] + kh1 * kwp[48 + n]
            + xv[n] * (qdds[n] + kddp[n]);
    p[n * plane] = r;
  }
}

// ---------------------------------------------------------------------------
// causal softmax in place on chunk (NH, TTCH, TS).  Block per (tloc, n).
// masked (s > t0+tloc) -> 0.
// ---------------------------------------------------------------------------
__global__ __launch_bounds__(256) void softmax_k(float* __restrict__ x, int t0) {
  const int tl = blockIdx.x, n = blockIdx.y, tid = threadIdx.x;
  const int tg = t0 + tl;
  float* row = x + ((size_t)n * TTCH + tl) * TS;
  float l[8];
  float m = -INFINITY;
  #pragma unroll
  for (int k = 0; k < 8; ++k) {
    int s = tid + k * 256;
    l[k] = (s <= tg) ? row[s] : -INFINITY;
    m = fmaxf(m, l[k]);
  }
  #pragma unroll
  for (int d = 1; d < 64; d <<= 1) m = fmaxf(m, __shfl_xor(m, d));
  __shared__ float red[4];
  if ((tid & 63) == 0) red[tid >> 6] = m;
  __syncthreads();
  m = fmaxf(fmaxf(red[0], red[1]), fmaxf(red[2], red[3]));
  float sum = 0.f;
  #pragma unroll
  for (int k = 0; k < 8; ++k) {
    int s = tid + k * 256;
    l[k] = (s <= tg) ? expf(l[k] - m) : 0.f;
    sum += l[k];
  }
  #pragma unroll
  for (int d = 1; d < 64; d <<= 1) sum += __shfl_xor(sum, d);
  __syncthreads();
  if ((tid & 63) == 0) red[tid >> 6] = sum;
  __syncthreads();
  sum = red[0] + red[1] + red[2] + red[3];
  const float isum = 1.0f / sum;
  #pragma unroll
  for (int k = 0; k < 8; ++k) row[tid + k * 256] = l[k] * isum;
}

// a *= b, float4 grid-stride
__global__ __launch_bounds__(256) void mul_k(float* __restrict__ a,
                                             const float* __restrict__ b,
                                             long n4) {
  long i = (long)blockIdx.x * 256 + threadIdx.x;
  const long stride = (long)gridDim.x * 256;
  for (; i < n4; i += stride) {
    float4 av = ((const float4*)a)[i];
    float4 bv = ((const float4*)b)[i];
    ((float4*)a)[i] = make_float4(av.x * bv.x, av.y * bv.y, av.z * bv.z, av.w * bv.w);
  }
}

// ---------------------------------------------------------------------------
extern "C" void kernel_launch(void* const* d_in, const int* in_sizes, int n_in,
                              void* d_out, int out_size, void* d_ws, size_t ws_size,
                              hipStream_t stream) {
  (void)in_sizes; (void)n_in; (void)out_size; (void)ws_size;
  const float* x    = (const float*)d_in[0];
  const float* anw  = (const float*)d_in[1];
  const float* wqkv = (const float*)d_in[2];
  const float* qnw  = (const float*)d_in[3];
  const float* knw  = (const float*)d_in[4];
  const float* dw1  = (const float*)d_in[5];
  const float* qkw  = (const float*)d_in[6];
  const float* dd   = (const float*)d_in[7];
  const float* wo   = (const float*)d_in[8];
  const float* fnw  = (const float*)d_in[9];
  const float* w1f  = (const float*)d_in[10];
  const float* w3f  = (const float*)d_in[11];
  const float* w2f  = (const float*)d_in[12];
  float* out = (float*)d_out;
  float* ws = (float*)d_ws;

  // Workspace layout (floats).  High-water: ~25.2M floats = 101 MB.
  const size_t SZ_D2 = (size_t)TS * DM;            // 4 M floats
  float* hn    = ws;                               // [0,4M)      (T, D)
  float* qkvb  = hn + SZ_D2;                       // [4M,16M)    (T, 3D); q/k roped in place
  float* dwh   = qkvb + (size_t)TS * 3 * DM;       // (T, 256)
  float* dynw  = dwh + (size_t)TS * 256;           // (T, 4,4,16)
  float* ddv   = dynw + (size_t)TS * 256;          // (T, 64)
  float* logc  = ddv + (size_t)TS * 64;            // (NH, TTCH, TS) 32 MB
  // Phase B (post-attention) — aliases dead Phase-A buffers:
  float* ob    = hn;                               // (T, D)  [hn dead after attn]
  float* hb    = qkvb;                             // (T, D)  [qkv dead]
  float* fnb   = qkvb + SZ_D2;                     // (T, D)
  float* g1c   = qkvb + 2 * SZ_D2;                 // (FCH, FF) chunk
  float* g3c   = g1c + (size_t)FCH * FF;           // (FCH, FF) chunk
  // Split-K partial scratch = d_out (16 MB, dead until final FFN writes it)
  float* part  = out;

  const int  ld3 = 3 * DM;                 // row stride inside qkv
  const long sLG = (long)TTCH * TS;        // per-head logits-chunk stride
  const float* qp = qkvb;                  // head n at qp + n*DH, lda=3D
  const float* kp = qkvb + DM;
  const float* vp = qkvb + 2 * DM;

  // 1. hn = rmsnorm(x, attn_norm_w)
  rmsnorm_k<<<TS, 256, 0, stream>>>(x, anw, hn);
  // 2. qkv = hn @ wqkv
  gemm_k<0,0><<<dim3(48, 16, 1), 256, 0, stream>>>(hn, wqkv, qkvb, nullptr,
      TS, 3*DM, DM, DM, 3*DM, 3*DM, 0, 0, 0);
  // 3. dyn-w pieces from hn — split-K (8 splits) to fill the chip
  gemm_splitk<<<dim3(2, 16, 8), 256, 0, stream>>>(hn, dw1, part,
      TS, 256, 256, DM, 256, 256, 0, 0, 0, (long)TS * 256, 8);
  reduce_k<1><<<512, 256, 0, stream>>>(part, dwh, (long)TS * 256 / 4,
      (long)TS * 256 / 4, 8);                              // gelu
  gemm_splitk<<<dim3(1, 16, 8), 256, 0, stream>>>(hn, dd, part,
      TS, 64, 256, DM, 64, 64, 0, 0, 0, (long)TS * 64, 8);
  reduce_k<2><<<128, 256, 0, stream>>>(part, ddv, (long)TS * 64 / 4,
      (long)TS * 64 / 4, 8);                               // tanh
  dynw_k<<<TS, 256, 0, stream>>>(dwh, qkw, dynw);
  // 4. q/k: rmsnorm + rope + q-scale, in place in qkvb
  qkrope_k<<<dim3(NH, TS), 64, 0, stream>>>(qkvb, qnw, knw);
  // 5-9. attention in query chunks of TTCH rows (32 MB scratch)
  for (int t0 = 0; t0 < TS; t0 += TTCH) {
    // logits chunk = q[t0:t0+TTCH] @ k^T   (batched over heads)
    gemm_k<1,0><<<dim3(16, TTCH/128, NH), 256, 0, stream>>>(
        qp + (size_t)t0 * ld3, kp, logc, nullptr,
        TTCH, TS, DH, ld3, ld3, TS, DH, DH, sLG);
    // cross_head_proj (pre), in place
    chp_k<<<dim3(8, TTCH), 256, 0, stream>>>(logc, dynw, ddv, 0, 1, 0, 16, t0);
    // causal softmax, in place (masked entries -> exactly 0)
    softmax_k<<<dim3(TTCH, NH), 256, 0, stream>>>(logc, t0);
    // cross_head_proj (post), in place (zero columns stay zero)
    chp_k<<<dim3(8, TTCH), 256, 0, stream>>>(logc, dynw, ddv, 2, 3, 32, 48, t0);
    // o chunk = probs @ v — split-K over K=TS (8 splits): 256 blocks
    gemm_splitk<<<dim3(1, TTCH/128, NH * 8), 256, 0, stream>>>(
        logc, vp, part, TTCH, DH, TS / 8, TS, ld3, DM,
        sLG, (long)DH, (long)DH, (long)TTCH * DM, 8);
    reduce_k<0><<<512, 256, 0, stream>>>(part, ob + (size_t)t0 * DM,
        (long)TTCH * DM / 4, (long)TTCH * DM / 4, 8);
  }
  // 10. h = x + o @ wo
  gemm_k<0,4><<<dim3(16, 16, 1), 256, 0, stream>>>(ob, wo, hb, x,
      TS, DM, DM, DM, DM, DM, 0, 0, 0);
  // 11. fn = rmsnorm(h, ffn_norm_w)
  rmsnorm_k<<<TS, 256, 0, stream>>>(hb, fnw, fnb);
  // 12-13. FFN in row chunks of FCH:
  //   g1 = silu(fn@w1f); g3 = fn@w3f; out = h + (g1*g3)@w2f
  for (int r0 = 0; r0 < TS; r0 += FCH) {
    const float* fr = fnb + (size_t)r0 * DM;
    gemm_k<0,3><<<dim3(44, FCH/128, 1), 256, 0, stream>>>(fr, w1f, g1c, nullptr,
        FCH, FF, DM, DM, FF, FF, 0, 0, 0);
    gemm_k<0,0><<<dim3(44, FCH/128, 1), 256, 0, stream>>>(fr, w3f, g3c, nullptr,
        FCH, FF, DM, DM, FF, FF, 0, 0, 0);
    mul_k<<<2048, 256, 0, stream>>>(g1c, g3c, (long)FCH * FF / 4);
    gemm_k<0,4><<<dim3(16, FCH/128, 1), 256, 0, stream>>>(g1c, w2f,
        out + (size_t)r0 * DM, hb + (size_t)r0 * DM,
        FCH, DM, FF, FF, DM, DM, 0, 0, 0);
  }
}

// Round 6
// 4433.896 us; speedup vs baseline: 2.4409x; 1.3078x over previous
//
#include <hip/hip_runtime.h>
#include <cmath>

// Problem constants (B=1)
#define TS 2048   // sequence length T
#define DM 2048   // model dim D
#define NH 16     // heads
#define DH 128    // head dim
#define FF 5632   // ffn dim
#define TTCH 256  // attention query-chunk rows
#define FCHG 1024 // ffn g1/g3 row-chunk
#define WCH 512   // ffn w2f row sub-chunk

// ---------------------------------------------------------------------------
// rmsnorm over rows of (rows, 2048), with weight
// ---------------------------------------------------------------------------
__global__ __launch_bounds__(256) void rmsnorm_k(const float* __restrict__ in,
                                                 const float* __restrict__ w,
                                                 float* __restrict__ out) {
  const int row = blockIdx.x;
  const int tid = threadIdx.x;
  const float* r = in + (size_t)row * DM;
  float4 v0 = ((const float4*)r)[tid];
  float4 v1 = ((const float4*)r)[tid + 256];
  float ss = v0.x*v0.x + v0.y*v0.y + v0.z*v0.z + v0.w*v0.w
           + v1.x*v1.x + v1.y*v1.y + v1.z*v1.z + v1.w*v1.w;
  #pragma unroll
  for (int d = 1; d < 64; d <<= 1) ss += __shfl_xor(ss, d);
  __shared__ float red[4];
  if ((tid & 63) == 0) red[tid >> 6] = ss;
  __syncthreads();
  ss = red[0] + red[1] + red[2] + red[3];
  const float sc = rsqrtf(ss * (1.0f / DM) + 1e-6f);
  float4 w0 = ((const float4*)w)[tid];
  float4 w1 = ((const float4*)w)[tid + 256];
  float* po = out + (size_t)row * DM;
  ((float4*)po)[tid]       = make_float4(v0.x*sc*w0.x, v0.y*sc*w0.y, v0.z*sc*w0.z, v0.w*sc*w0.w);
  ((float4*)po)[tid + 256] = make_float4(v1.x*sc*w1.x, v1.y*sc*w1.y, v1.z*sc*w1.z, v1.w*sc*w1.w);
}

// ---------------------------------------------------------------------------
// Tiled fp32 GEMM.  TB=0: B (K,N) row-major.  TB=1: B (N,K), A@B^T.
// PACKH=1: C write remapped to per-head packed layout:
//   C[(gc>>7)*(TS*DH) + gr*DH + (gc&127)]   (ldc ignored)
// BM=BN=128, BK=16, 256 threads, 8x8 micro-tile.
// ---------------------------------------------------------------------------
template<int TB, int PACKH>
__global__ __launch_bounds__(256) void gemm_k(
    const float* __restrict__ A, const float* __restrict__ B,
    float* __restrict__ C,
    int M, int N, int K, int lda, int ldb, int ldc,
    long sA, long sB, long sC) {
  const int z = blockIdx.z;
  A += (size_t)z * sA; B += (size_t)z * sB; C += (size_t)z * sC;
  const int n0 = blockIdx.x * 128, m0 = blockIdx.y * 128;
  const int tid = threadIdx.x;
  const int tr = tid >> 4, tc = tid & 15;
  __shared__ float As[16][132];
  __shared__ float Bs[16][132];
  float acc[8][8];
  #pragma unroll
  for (int i = 0; i < 8; ++i)
    #pragma unroll
    for (int j = 0; j < 8; ++j) acc[i][j] = 0.f;

  for (int k0 = 0; k0 < K; k0 += 16) {
    #pragma unroll
    for (int l = 0; l < 2; ++l) {
      int fi = tid + l * 256;
      int row = fi >> 2, kq = fi & 3;
      float4 av = *(const float4*)&A[(size_t)(m0 + row) * lda + k0 + kq * 4];
      As[kq*4+0][row] = av.x; As[kq*4+1][row] = av.y;
      As[kq*4+2][row] = av.z; As[kq*4+3][row] = av.w;
    }
    if (TB == 0) {
      #pragma unroll
      for (int l = 0; l < 2; ++l) {
        int fi = tid + l * 256;
        int kr = fi >> 5, cq = fi & 31;
        int gc = n0 + cq * 4;
        float4 bv = make_float4(0.f, 0.f, 0.f, 0.f);
        if (gc < N) bv = *(const float4*)&B[(size_t)(k0 + kr) * ldb + gc];
        *(float4*)&Bs[kr][cq * 4] = bv;
      }
    } else {
      #pragma unroll
      for (int l = 0; l < 2; ++l) {
        int fi = tid + l * 256;
        int col = fi >> 2, kq = fi & 3;
        int gc = n0 + col;
        float4 bv = make_float4(0.f, 0.f, 0.f, 0.f);
        if (gc < N) bv = *(const float4*)&B[(size_t)gc * ldb + k0 + kq * 4];
        Bs[kq*4+0][col] = bv.x; Bs[kq*4+1][col] = bv.y;
        Bs[kq*4+2][col] = bv.z; Bs[kq*4+3][col] = bv.w;
      }
    }
    __syncthreads();
    #pragma unroll
    for (int kk = 0; kk < 16; ++kk) {
      float a[8], b[8];
      *(float4*)&a[0] = *(const float4*)&As[kk][tr * 8];
      *(float4*)&a[4] = *(const float4*)&As[kk][tr * 8 + 4];
      *(float4*)&b[0] = *(const float4*)&Bs[kk][tc * 4];
      *(float4*)&b[4] = *(const float4*)&Bs[kk][64 + tc * 4];
      #pragma unroll
      for (int i = 0; i < 8; ++i)
        #pragma unroll
        for (int j = 0; j < 8; ++j)
          acc[i][j] = fmaf(a[i], b[j], acc[i][j]);
    }
    __syncthreads();
  }

  #pragma unroll
  for (int i = 0; i < 8; ++i) {
    int gr = m0 + tr * 8 + i;
    #pragma unroll
    for (int half = 0; half < 2; ++half) {
      int gc = n0 + half * 64 + tc * 4;
      if (gc < N) {
        float4 v = make_float4(acc[i][half*4], acc[i][half*4+1],
                               acc[i][half*4+2], acc[i][half*4+3]);
        if (PACKH) {
          *(float4*)&C[(size_t)(gc >> 7) * ((size_t)TS * DH)
                       + (size_t)gr * DH + (gc & 127)] = v;
        } else {
          *(float4*)&C[(size_t)gr * ldc + gc] = v;
        }
      }
    }
  }
}

// ---------------------------------------------------------------------------
// Split-K fp32 GEMM partial (TB=0 layout): P = A[krange] @ B[krange]
// grid.z = batch * NS + split.  AMUL=1: A_eff[i] = A[i]*A2[i] (elementwise).
// ---------------------------------------------------------------------------
template<int AMUL>
__global__ __launch_bounds__(256) void gemm_splitk(
    const float* __restrict__ A, const float* __restrict__ A2,
    const float* __restrict__ B, float* __restrict__ P,
    int M, int N, int Kps, int lda, int ldb, int ldc,
    long sAb, long sBb, long cColb, long sCsp, int NS) {
  const int bt = blockIdx.z / NS, sp = blockIdx.z % NS;
  A += (size_t)bt * sAb + (size_t)sp * Kps;
  if (AMUL) A2 += (size_t)bt * sAb + (size_t)sp * Kps;
  B += (size_t)bt * sBb + (size_t)sp * Kps * ldb;
  P += (size_t)sp * sCsp + (size_t)bt * cColb;
  const int n0 = blockIdx.x * 128, m0 = blockIdx.y * 128;
  const int tid = threadIdx.x;
  const int tr = tid >> 4, tc = tid & 15;
  __shared__ float As[16][132];
  __shared__ float Bs[16][132];
  float acc[8][8];
  #pragma unroll
  for (int i = 0; i < 8; ++i)
    #pragma unroll
    for (int j = 0; j < 8; ++j) acc[i][j] = 0.f;

  for (int k0 = 0; k0 < Kps; k0 += 16) {
    #pragma unroll
    for (int l = 0; l < 2; ++l) {
      int fi = tid + l * 256;
      int row = fi >> 2, kq = fi & 3;
      size_t ai = (size_t)(m0 + row) * lda + k0 + kq * 4;
      float4 av = *(const float4*)&A[ai];
      if (AMUL) {
        float4 a2 = *(const float4*)&A2[ai];
        av.x *= a2.x; av.y *= a2.y; av.z *= a2.z; av.w *= a2.w;
      }
      As[kq*4+0][row] = av.x; As[kq*4+1][row] = av.y;
      As[kq*4+2][row] = av.z; As[kq*4+3][row] = av.w;
    }
    #pragma unroll
    for (int l = 0; l < 2; ++l) {
      int fi = tid + l * 256;
      int kr = fi >> 5, cq = fi & 31;
      int gc = n0 + cq * 4;
      float4 bv = make_float4(0.f, 0.f, 0.f, 0.f);
      if (gc < N) bv = *(const float4*)&B[(size_t)(k0 + kr) * ldb + gc];
      *(float4*)&Bs[kr][cq * 4] = bv;
    }
    __syncthreads();
    #pragma unroll
    for (int kk = 0; kk < 16; ++kk) {
      float a[8], b[8];
      *(float4*)&a[0] = *(const float4*)&As[kk][tr * 8];
      *(float4*)&a[4] = *(const float4*)&As[kk][tr * 8 + 4];
      *(float4*)&b[0] = *(const float4*)&Bs[kk][tc * 4];
      *(float4*)&b[4] = *(const float4*)&Bs[kk][64 + tc * 4];
      #pragma unroll
      for (int i = 0; i < 8; ++i)
        #pragma unroll
        for (int j = 0; j < 8; ++j)
          acc[i][j] = fmaf(a[i], b[j], acc[i][j]);
    }
    __syncthreads();
  }

  #pragma unroll
  for (int i = 0; i < 8; ++i) {
    int gr = m0 + tr * 8 + i;
    #pragma unroll
    for (int half = 0; half < 2; ++half) {
      int gc = n0 + half * 64 + tc * 4;
      if (gc < N)
        *(float4*)&P[(size_t)gr * ldc + gc] =
            make_float4(acc[i][half*4], acc[i][half*4+1],
                        acc[i][half*4+2], acc[i][half*4+3]);
    }
  }
}

// ---------------------------------------------------------------------------
// Dual-B FFN GEMM: z=0: C=silu(A@B1); z=1: C+sC = A@B3.  M=FCHG,N=FF,K=DM.
// ---------------------------------------------------------------------------
__global__ __launch_bounds__(256) void gemm_ffn(
    const float* __restrict__ A, const float* __restrict__ B1,
    const float* __restrict__ B3, float* __restrict__ C, long sC) {
  const int z = blockIdx.z;
  const float* B = z ? B3 : B1;
  C += (size_t)z * sC;
  const int n0 = blockIdx.x * 128, m0 = blockIdx.y * 128;
  const int tid = threadIdx.x;
  const int tr = tid >> 4, tc = tid & 15;
  __shared__ float As[16][132];
  __shared__ float Bs[16][132];
  float acc[8][8];
  #pragma unroll
  for (int i = 0; i < 8; ++i)
    #pragma unroll
    for (int j = 0; j < 8; ++j) acc[i][j] = 0.f;

  for (int k0 = 0; k0 < DM; k0 += 16) {
    #pragma unroll
    for (int l = 0; l < 2; ++l) {
      int fi = tid + l * 256;
      int row = fi >> 2, kq = fi & 3;
      float4 av = *(const float4*)&A[(size_t)(m0 + row) * DM + k0 + kq * 4];
      As[kq*4+0][row] = av.x; As[kq*4+1][row] = av.y;
      As[kq*4+2][row] = av.z; As[kq*4+3][row] = av.w;
    }
    #pragma unroll
    for (int l = 0; l < 2; ++l) {
      int fi = tid + l * 256;
      int kr = fi >> 5, cq = fi & 31;
      int gc = n0 + cq * 4;
      float4 bv = *(const float4*)&B[(size_t)(k0 + kr) * FF + gc];
      *(float4*)&Bs[kr][cq * 4] = bv;
    }
    __syncthreads();
    #pragma unroll
    for (int kk = 0; kk < 16; ++kk) {
      float a[8], b[8];
      *(float4*)&a[0] = *(const float4*)&As[kk][tr * 8];
      *(float4*)&a[4] = *(const float4*)&As[kk][tr * 8 + 4];
      *(float4*)&b[0] = *(const float4*)&Bs[kk][tc * 4];
      *(float4*)&b[4] = *(const float4*)&Bs[kk][64 + tc * 4];
      #pragma unroll
      for (int i = 0; i < 8; ++i)
        #pragma unroll
        for (int j = 0; j < 8; ++j)
          acc[i][j] = fmaf(a[i], b[j], acc[i][j]);
    }
    __syncthreads();
  }

  #pragma unroll
  for (int i = 0; i < 8; ++i) {
    int gr = m0 + tr * 8 + i;
    #pragma unroll
    for (int half = 0; half < 2; ++half) {
      int gc = n0 + half * 64 + tc * 4;
      float v[4];
      #pragma unroll
      for (int j = 0; j < 4; ++j) {
        float t = acc[i][half * 4 + j];
        if (z == 0) t = t / (1.0f + expf(-t));   // silu
        v[j] = t;
      }
      *(float4*)&C[(size_t)gr * FF + gc] = make_float4(v[0], v[1], v[2], v[3]);
    }
  }
}

// ---------------------------------------------------------------------------
// reduce NS split partials (float4), apply epilogue.
// EPI: 0 none, 1 gelu(exact), 2 tanh, 3 add residual R
// ---------------------------------------------------------------------------
template<int EPI>
__global__ __launch_bounds__(256) void reduce_k(const float* __restrict__ P,
                                                const float* __restrict__ R,
                                                float* __restrict__ out,
                                                long n4, long sSp4, int NS) {
  long i = (long)blockIdx.x * 256 + threadIdx.x;
  const long stride = (long)gridDim.x * 256;
  for (; i < n4; i += stride) {
    float4 s = ((const float4*)P)[i];
    for (int sp = 1; sp < NS; ++sp) {
      float4 v = ((const float4*)P)[i + sp * sSp4];
      s.x += v.x; s.y += v.y; s.z += v.z; s.w += v.w;
    }
    if (EPI == 1) {
      s.x = 0.5f*s.x*(1.0f+erff(s.x*0.70710678118654752f));
      s.y = 0.5f*s.y*(1.0f+erff(s.y*0.70710678118654752f));
      s.z = 0.5f*s.z*(1.0f+erff(s.z*0.70710678118654752f));
      s.w = 0.5f*s.w*(1.0f+erff(s.w*0.70710678118654752f));
    } else if (EPI == 2) {
      s.x = tanhf(s.x); s.y = tanhf(s.y); s.z = tanhf(s.z); s.w = tanhf(s.w);
    } else if (EPI == 3) {
      float4 rv = ((const float4*)R)[i];
      s.x += rv.x; s.y += rv.y; s.z += rv.z; s.w += rv.w;
    }
    ((float4*)out)[i] = s;
  }
}

// ---------------------------------------------------------------------------
// Per-(head, t) on PACKED qkv (48, T, DH): rmsnorm(q), rmsnorm(k), RoPE both,
// scale q by Dh^-0.5.  In place.  Head n: q at n, k at NH+n.
// ---------------------------------------------------------------------------
__global__ __launch_bounds__(64) void qkrope_k(float* __restrict__ qkvp,
                                               const float* __restrict__ qnw,
                                               const float* __restrict__ knw) {
  const int n = blockIdx.x, t = blockIdx.y, i = threadIdx.x;
  float* qr = qkvp + ((size_t)n * TS + t) * DH;
  float* kr = qkvp + ((size_t)(NH + n) * TS + t) * DH;
  float q1 = qr[i], q2 = qr[i + 64];
  float k1 = kr[i], k2 = kr[i + 64];
  float ssq = q1 * q1 + q2 * q2;
  float ssk = k1 * k1 + k2 * k2;
  #pragma unroll
  for (int d = 1; d < 64; d <<= 1) {
    ssq += __shfl_xor(ssq, d);
    ssk += __shfl_xor(ssk, d);
  }
  const float rq = rsqrtf(ssq * (1.0f / DH) + 1e-6f);
  const float rk = rsqrtf(ssk * (1.0f / DH) + 1e-6f);
  float qn1 = q1 * rq * qnw[i], qn2 = q2 * rq * qnw[i + 64];
  float kn1 = k1 * rk * knw[i], kn2 = k2 * rk * knw[i + 64];
  float inv = 1.0f / powf(10000.0f, (float)i * (1.0f / 64.0f));
  float ang = (float)t * inv;
  float c = (float)cos((double)ang);
  float s = (float)sin((double)ang);
  const float scale = 0.08838834764831845f;  // 128^-0.5 (q only)
  qr[i]      = (qn1 * c - qn2 * s) * scale;
  qr[i + 64] = (qn2 * c + qn1 * s) * scale;
  kr[i]      = kn1 * c - kn2 * s;
  kr[i + 64] = kn2 * c + kn1 * s;
}

// ---------------------------------------------------------------------------
// dyn-w: w[t,c,i,n] = sum_kk dwh[t,c,kk]*qkw[c,kk,i,n]; rmsnorm_noscale over
// n (16) for i<2.  One block per t; wave c; 16-lane groups share (c,i).
// ---------------------------------------------------------------------------
__global__ __launch_bounds__(256) void dynw_k(const float* __restrict__ dwh,
                                              const float* __restrict__ qkw,
                                              float* __restrict__ dynw) {
  const int t = blockIdx.x, tid = threadIdx.x;
  __shared__ float dwhs[256];
  dwhs[tid] = dwh[(size_t)t * 256 + tid];
  __syncthreads();
  const int c = tid >> 6, r = tid & 63, ifull = r >> 4, n = r & 15;
  const float* qp = qkw + (size_t)(c * 64) * 64 + ifull * 16 + n;
  const float* dp = dwhs + c * 64;
  float acc = 0.f;
  #pragma unroll 8
  for (int kk = 0; kk < 64; ++kk) acc = fmaf(dp[kk], qp[(size_t)kk * 64], acc);
  float ss = acc * acc;
  #pragma unroll
  for (int m = 1; m < 16; m <<= 1) ss += __shfl_xor(ss, m);
  float v = (ifull < 2) ? acc * rsqrtf(ss * (1.0f / 16) + 1e-6f) : acc;
  dynw[(size_t)t * 256 + tid] = v;
}

// ---------------------------------------------------------------------------
// cross_head_proj, in place on a logits CHUNK x (NH, TTCH, TS).
// ---------------------------------------------------------------------------
__global__ __launch_bounds__(256) void chp_k(float* __restrict__ x,
                                             const float* __restrict__ dynw,
                                             const float* __restrict__ ddv,
                                             int cq, int ck, int oq, int ok,
                                             int t0) {
  const int tl = blockIdx.y;
  const int tg = t0 + tl;
  const int s = blockIdx.x * 256 + threadIdx.x;
  const int tid = threadIdx.x;
  __shared__ float qw[64];
  __shared__ float qdds[16];
  if (tid < 64) qw[tid] = dynw[(size_t)tg * 256 + cq * 64 + tid];
  else if (tid < 80) qdds[tid - 64] = ddv[(size_t)tg * 64 + oq + (tid - 64)];
  __syncthreads();
  const size_t plane = (size_t)TTCH * TS;
  float* p = x + (size_t)tl * TS + s;
  float xv[16];
  #pragma unroll
  for (int n = 0; n < 16; ++n) xv[n] = p[n * plane];
  float qh0 = 0.f, qh1 = 0.f, kh0 = 0.f, kh1 = 0.f;
  const float* kwp = dynw + (size_t)s * 256 + ck * 64;
  #pragma unroll
  for (int n = 0; n < 16; ++n) {
    qh0 = fmaf(xv[n], qw[n], qh0);
    qh1 = fmaf(xv[n], qw[16 + n], qh1);
    kh0 = fmaf(xv[n], kwp[n], kh0);
    kh1 = fmaf(xv[n], kwp[16 + n], kh1);
  }
  const float* kddp = ddv + (size_t)s * 64 + ok;
  #pragma unroll
  for (int n = 0; n < 16; ++n) {
    float r = xv[n]
            + qh0 * qw[32 + n] + qh1 * qw[48 + n]
            + kh0 * kwp[32 + n] + kh1 * kwp[48 + n]
            + xv[n] * (qdds[n] + kddp[n]);
    p[n * plane] = r;
  }
}

// ---------------------------------------------------------------------------
// causal softmax in place on chunk (NH, TTCH, TS).
// ---------------------------------------------------------------------------
__global__ __launch_bounds__(256) void softmax_k(float* __restrict__ x, int t0) {
  const int tl = blockIdx.x, n = blockIdx.y, tid = threadIdx.x;
  const int tg = t0 + tl;
  float* row = x + ((size_t)n * TTCH + tl) * TS;
  float l[8];
  float m = -INFINITY;
  #pragma unroll
  for (int k = 0; k < 8; ++k) {
    int s = tid + k * 256;
    l[k] = (s <= tg) ? row[s] : -INFINITY;
    m = fmaxf(m, l[k]);
  }
  #pragma unroll
  for (int d = 1; d < 64; d <<= 1) m = fmaxf(m, __shfl_xor(m, d));
  __shared__ float red[4];
  if ((tid & 63) == 0) red[tid >> 6] = m;
  __syncthreads();
  m = fmaxf(fmaxf(red[0], red[1]), fmaxf(red[2], red[3]));
  float sum = 0.f;
  #pragma unroll
  for (int k = 0; k < 8; ++k) {
    int s = tid + k * 256;
    l[k] = (s <= tg) ? expf(l[k] - m) : 0.f;
    sum += l[k];
  }
  #pragma unroll
  for (int d = 1; d < 64; d <<= 1) sum += __shfl_xor(sum, d);
  __syncthreads();
  if ((tid & 63) == 0) red[tid >> 6] = sum;
  __syncthreads();
  sum = red[0] + red[1] + red[2] + red[3];
  const float isum = 1.0f / sum;
  #pragma unroll
  for (int k = 0; k < 8; ++k) row[tid + k * 256] = l[k] * isum;
}

// ---------------------------------------------------------------------------
extern "C" void kernel_launch(void* const* d_in, const int* in_sizes, int n_in,
                              void* d_out, int out_size, void* d_ws, size_t ws_size,
                              hipStream_t stream) {
  (void)in_sizes; (void)n_in; (void)out_size; (void)ws_size;
  const float* x    = (const float*)d_in[0];
  const float* anw  = (const float*)d_in[1];
  const float* wqkv = (const float*)d_in[2];
  const float* qnw  = (const float*)d_in[3];
  const float* knw  = (const float*)d_in[4];
  const float* dw1  = (const float*)d_in[5];
  const float* qkw  = (const float*)d_in[6];
  const float* dd   = (const float*)d_in[7];
  const float* wo   = (const float*)d_in[8];
  const float* fnw  = (const float*)d_in[9];
  const float* w1f  = (const float*)d_in[10];
  const float* w3f  = (const float*)d_in[11];
  const float* w2f  = (const float*)d_in[12];
  float* out = (float*)d_out;
  float* ws = (float*)d_ws;

  // Workspace layout (floats). High-water 26,345,472 floats = 105.4 MB
  // (identical to the round-4/5 proven footprint).
  const size_t SZ_D2 = (size_t)TS * DM;            // 4,194,304
  const size_t SZ_H  = (size_t)TS * DH;            // 262,144 per head
  // Phase A (attention):
  float* hn    = ws;                               // [0, 4.19M)
  float* qkvp  = hn + SZ_D2;                       // [4.19M, 16.78M) packed (48,T,128)
  float* dwh   = qkvp + (size_t)TS * 3 * DM;       // 0.52M
  float* dynw  = dwh + (size_t)TS * 256;           // 0.52M
  float* ddv   = dynw + (size_t)TS * 256;          // 0.13M
  float* logc  = ddv + (size_t)TS * 64;            // [17.96M, 26.35M)
  float* qb    = qkvp;
  float* kb    = qkvp + NH * SZ_H;
  float* vb    = qkvp + 2 * NH * SZ_H;
  // Phase B (post-attention) — aliases dead Phase-A regions:
  float* ob    = hn;                               // (T,D) [hn dead]
  float* pwo   = dwh;                              // wo partials 2x4M [16.78M, 25.17M)
  float* hb    = qkvp;                             // (T,D) at [4.19M, 8.39M) [qkv dead]
  float* fnb   = hn;                               // (T,D) [ob dead after wo]
  float* g1c   = qkvp + SZ_D2;                     // [8.39M, 14.16M) (FCHG,FF)
  float* g3c   = g1c + (size_t)FCHG * FF;          // [14.16M, 19.92M)
  float* pw2   = g3c + (size_t)FCHG * FF;          // [19.92M, 24.12M) 4x(WCH,DM)
  // split-K partials for dwh/ddv/PV live in d_out (dead until FFN writes it)
  float* part  = out;

  const long sLG = (long)TTCH * TS;

  // 1. hn = rmsnorm(x, attn_norm_w)
  rmsnorm_k<<<TS, 256, 0, stream>>>(x, anw, hn);
  // 2. qkv = hn @ wqkv, written PACKED per head (48, T, 128)
  gemm_k<0,1><<<dim3(48, 16, 1), 256, 0, stream>>>(hn, wqkv, qkvp,
      TS, 3*DM, DM, DM, 3*DM, 0, 0, 0, 0);
  // 3. dyn-w pieces (split-K 8, partials in d_out)
  gemm_splitk<0><<<dim3(2, 16, 8), 256, 0, stream>>>(hn, nullptr, dw1, part,
      TS, 256, 256, DM, 256, 256, 0, 0, 0, (long)TS * 256, 8);
  reduce_k<1><<<512, 256, 0, stream>>>(part, nullptr, dwh,
      (long)TS * 256 / 4, (long)TS * 256 / 4, 8);          // gelu
  gemm_splitk<0><<<dim3(1, 16, 8), 256, 0, stream>>>(hn, nullptr, dd, part,
      TS, 64, 256, DM, 64, 64, 0, 0, 0, (long)TS * 64, 8);
  reduce_k<2><<<128, 256, 0, stream>>>(part, nullptr, ddv,
      (long)TS * 64 / 4, (long)TS * 64 / 4, 8);            // tanh
  dynw_k<<<TS, 256, 0, stream>>>(dwh, qkw, dynw);
  // 4. q/k: rmsnorm + rope + q-scale, in place on packed layout
  qkrope_k<<<dim3(NH, TS), 64, 0, stream>>>(qkvp, qnw, knw);
  // 5-9. attention in query chunks of TTCH rows
  for (int t0 = 0; t0 < TS; t0 += TTCH) {
    // logits = q_chunk @ k^T  (contiguous per-head operands, lda=ldb=128)
    gemm_k<1,0><<<dim3(16, TTCH/128, NH), 256, 0, stream>>>(
        qb + (size_t)t0 * DH, kb, logc,
        TTCH, TS, DH, DH, DH, TS, (long)SZ_H, (long)SZ_H, sLG);
    chp_k<<<dim3(8, TTCH), 256, 0, stream>>>(logc, dynw, ddv, 0, 1, 0, 16, t0);
    softmax_k<<<dim3(TTCH, NH), 256, 0, stream>>>(logc, t0);
    chp_k<<<dim3(8, TTCH), 256, 0, stream>>>(logc, dynw, ddv, 2, 3, 32, 48, t0);
    // o chunk = probs @ v  (split-K 8; partials fill d_out exactly)
    gemm_splitk<0><<<dim3(1, TTCH/128, NH * 8), 256, 0, stream>>>(
        logc, nullptr, vb, part, TTCH, DH, TS / 8, TS, DH, DM,
        sLG, (long)SZ_H, (long)DH, (long)TTCH * DM, 8);
    reduce_k<0><<<512, 256, 0, stream>>>(part, nullptr, ob + (size_t)t0 * DM,
        (long)TTCH * DM / 4, (long)TTCH * DM / 4, 8);
  }
  // 10. h = x + o @ wo  (split-K 2, partials in ws; residual in reduce)
  gemm_splitk<0><<<dim3(16, 16, 2), 256, 0, stream>>>(ob, nullptr, wo, pwo,
      TS, DM, DM / 2, DM, DM, DM, 0, 0, 0, (long)TS * DM, 2);
  reduce_k<3><<<2048, 256, 0, stream>>>(pwo, x, hb,
      (long)TS * DM / 4, (long)TS * DM / 4, 2);
  // 11. fn = rmsnorm(h, ffn_norm_w)
  rmsnorm_k<<<TS, 256, 0, stream>>>(hb, fnw, fnb);
  // 12-13. FFN: per 1024-row chunk: merged silu(fn@w1f) | fn@w3f, then
  // per 512-row sub-chunk: (g1*g3) @ w2f split-K 4 + residual reduce.
  for (int r0 = 0; r0 < TS; r0 += FCHG) {
    gemm_ffn<<<dim3(44, FCHG/128, 2), 256, 0, stream>>>(
        fnb + (size_t)r0 * DM, w1f, w3f, g1c, (long)FCHG * FF);
    for (int sub = 0; sub < FCHG; sub += WCH) {
      const float* a1 = g1c + (size_t)sub * FF;
      const float* a3 = g3c + (size_t)sub * FF;
      gemm_splitk<1><<<dim3(16, WCH/128, 4), 256, 0, stream>>>(
          a1, a3, w2f, pw2, WCH, DM, FF / 4, FF, DM, DM,
          0, 0, 0, (long)WCH * DM, 4);
      reduce_k<3><<<1024, 256, 0, stream>>>(pw2, hb + (size_t)(r0 + sub) * DM,
          out + (size_t)(r0 + sub) * DM,
          (long)WCH * DM / 4, (long)WCH * DM / 4, 4);
    }
  }
}

// Round 7
// 2816.099 us; speedup vs baseline: 3.8432x; 1.5745x over previous
//
#include <hip/hip_runtime.h>
#include <hip/hip_bf16.h>
#include <cmath>

// Problem constants (B=1)
#define TS 2048   // sequence length T
#define DM 2048   // model dim D
#define NH 16     // heads
#define DH 128    // head dim
#define FF 5632   // ffn dim
#define TTCH 256  // attention query-chunk rows
#define FCHG 1024 // ffn row-chunk

typedef __attribute__((ext_vector_type(8))) short bf16x8;
typedef __attribute__((ext_vector_type(4))) float f32x4;
typedef __attribute__((ext_vector_type(4))) unsigned int u32x4;

union BFU { __hip_bfloat16 b; unsigned short u; };
__device__ __forceinline__ unsigned short f2h(float x) {
  BFU c; c.b = __float2bfloat16(x); return c.u;
}
__device__ __forceinline__ float h2f(unsigned short u) {
  BFU c; c.u = u; return __bfloat162float(c.b);
}
// split x into hi bf16 + lo bf16 (x ~= hi + lo, residual ~2^-18 |x|)
__device__ __forceinline__ void split2(float x, unsigned short& h, unsigned short& l) {
  h = f2h(x);
  l = f2h(x - h2f(h));
}

// ---------------------------------------------------------------------------
// rmsnorm over rows of (rows, 2048), with weight
// ---------------------------------------------------------------------------
__global__ __launch_bounds__(256) void rmsnorm_k(const float* __restrict__ in,
                                                 const float* __restrict__ w,
                                                 float* __restrict__ out) {
  const int row = blockIdx.x;
  const int tid = threadIdx.x;
  const float* r = in + (size_t)row * DM;
  float4 v0 = ((const float4*)r)[tid];
  float4 v1 = ((const float4*)r)[tid + 256];
  float ss = v0.x*v0.x + v0.y*v0.y + v0.z*v0.z + v0.w*v0.w
           + v1.x*v1.x + v1.y*v1.y + v1.z*v1.z + v1.w*v1.w;
  #pragma unroll
  for (int d = 1; d < 64; d <<= 1) ss += __shfl_xor(ss, d);
  __shared__ float red[4];
  if ((tid & 63) == 0) red[tid >> 6] = ss;
  __syncthreads();
  ss = red[0] + red[1] + red[2] + red[3];
  const float sc = rsqrtf(ss * (1.0f / DM) + 1e-6f);
  float4 w0 = ((const float4*)w)[tid];
  float4 w1 = ((const float4*)w)[tid + 256];
  float* po = out + (size_t)row * DM;
  ((float4*)po)[tid]       = make_float4(v0.x*sc*w0.x, v0.y*sc*w0.y, v0.z*sc*w0.z, v0.w*sc*w0.w);
  ((float4*)po)[tid + 256] = make_float4(v1.x*sc*w1.x, v1.y*sc*w1.y, v1.z*sc*w1.z, v1.w*sc*w1.w);
}

// ---------------------------------------------------------------------------
// MFMA split-bf16 GEMM (fp32-accurate): C = A @ B, A (M,K) row-major,
// B (K,N) row-major.  128x128 tile, BK=32, 4 waves, mfma_f32_16x16x32_bf16,
// 3 MFMA per fragment (hh + lh + hl).
// MODE 0: qkv — C write remapped to packed head layout (48,T,128).
// MODE 1: dual-B via blockIdx.z (z0: silu(A@B1) -> C; z1: A@B3 -> C+sCz).
// MODE 2: split-K partial, A_eff = A*A2 elementwise (w2f); z=split.
// MODE 3: split-K partial plain (wo); z=split.
// Requires M%128==0, N%128==0, Kps%32==0.
// ---------------------------------------------------------------------------
template<int MODE>
__global__ __launch_bounds__(256) void mfgemm(
    const float* __restrict__ A, const float* __restrict__ A2,
    const float* __restrict__ B1, const float* __restrict__ B3,
    float* __restrict__ C,
    int M, int N, int Kps, int lda, int ldb, int ldc, long sCz) {
  const int z = blockIdx.z;
  const float* B = B1;
  if (MODE == 1) { B = z ? B3 : B1; C += (size_t)z * sCz; }
  if (MODE == 2 || MODE == 3) {
    A += (size_t)z * Kps;
    if (MODE == 2) A2 += (size_t)z * Kps;
    B = B1 + (size_t)z * Kps * ldb;
    C += (size_t)z * sCz;
  }
  const int n0 = blockIdx.x * 128, m0 = blockIdx.y * 128;
  const int tid = threadIdx.x;
  const int lane = tid & 63, wid = tid >> 6;
  const int wm = wid >> 1, wn = wid & 1;          // 2x2 wave grid, 64x64 each
  const int lr = lane & 15, kb = lane >> 4;       // fragment row/col, k-chunk

  __shared__ unsigned short Ah[128][40];          // hi bf16, padded (80B rows)
  __shared__ unsigned short Al[128][40];          // lo bf16
  __shared__ unsigned int   Bu[128][36];          // [n][k] packed {hi | lo<<16}

  f32x4 acc[4][4];
  #pragma unroll
  for (int i = 0; i < 4; ++i)
    #pragma unroll
    for (int j = 0; j < 4; ++j)
      acc[i][j] = (f32x4){0.f, 0.f, 0.f, 0.f};

  for (int k0 = 0; k0 < Kps; k0 += 32) {
    // ---- stage A (128 rows x 32 k), split into hi/lo ----
    #pragma unroll
    for (int l = 0; l < 4; ++l) {
      int fi = tid + l * 256;
      int row = fi >> 3, kq = fi & 7;
      size_t ai = (size_t)(m0 + row) * lda + k0 + kq * 4;
      float4 av = *(const float4*)&A[ai];
      if (MODE == 2) {
        float4 a2 = *(const float4*)&A2[ai];
        av.x *= a2.x; av.y *= a2.y; av.z *= a2.z; av.w *= a2.w;
      }
      unsigned short h, lo;
      split2(av.x, h, lo); Ah[row][kq*4+0] = h; Al[row][kq*4+0] = lo;
      split2(av.y, h, lo); Ah[row][kq*4+1] = h; Al[row][kq*4+1] = lo;
      split2(av.z, h, lo); Ah[row][kq*4+2] = h; Al[row][kq*4+2] = lo;
      split2(av.w, h, lo); Ah[row][kq*4+3] = h; Al[row][kq*4+3] = lo;
    }
    // ---- stage B (32 k x 128 n) transposed to [n][k], packed hi|lo ----
    #pragma unroll
    for (int l = 0; l < 16; ++l) {
      int fi = tid + l * 256;
      int kr = fi >> 7, n = fi & 127;
      float bv = B[(size_t)(k0 + kr) * ldb + n0 + n];
      unsigned short h, lo;
      split2(bv, h, lo);
      Bu[n][kr] = (unsigned int)h | ((unsigned int)lo << 16);
    }
    __syncthreads();
    // ---- fragments ----
    bf16x8 ah[4], al[4], bh[4], bl[4];
    #pragma unroll
    for (int f = 0; f < 4; ++f) {
      ah[f] = *(const bf16x8*)&Ah[wm*64 + f*16 + lr][kb*8];
      al[f] = *(const bf16x8*)&Al[wm*64 + f*16 + lr][kb*8];
      const unsigned int* bp = &Bu[wn*64 + f*16 + lr][kb*8];
      u32x4 u0 = *(const u32x4*)bp;
      u32x4 u1 = *(const u32x4*)(bp + 4);
      union { bf16x8 v; unsigned short s[8]; } H, L;
      #pragma unroll
      for (int j = 0; j < 4; ++j) {
        H.s[j]   = (unsigned short)(u0[j] & 0xffffu);
        L.s[j]   = (unsigned short)(u0[j] >> 16);
        H.s[4+j] = (unsigned short)(u1[j] & 0xffffu);
        L.s[4+j] = (unsigned short)(u1[j] >> 16);
      }
      bh[f] = H.v; bl[f] = L.v;
    }
    #pragma unroll
    for (int mf = 0; mf < 4; ++mf)
      #pragma unroll
      for (int nf = 0; nf < 4; ++nf) {
        acc[mf][nf] = __builtin_amdgcn_mfma_f32_16x16x32_bf16(ah[mf], bh[nf], acc[mf][nf], 0, 0, 0);
        acc[mf][nf] = __builtin_amdgcn_mfma_f32_16x16x32_bf16(al[mf], bh[nf], acc[mf][nf], 0, 0, 0);
        acc[mf][nf] = __builtin_amdgcn_mfma_f32_16x16x32_bf16(ah[mf], bl[nf], acc[mf][nf], 0, 0, 0);
      }
    __syncthreads();
  }

  // ---- epilogue ----
  #pragma unroll
  for (int mf = 0; mf < 4; ++mf)
    #pragma unroll
    for (int nf = 0; nf < 4; ++nf)
      #pragma unroll
      for (int r = 0; r < 4; ++r) {
        int gr = m0 + wm*64 + mf*16 + kb*4 + r;   // C row (verified layout)
        int gc = n0 + wn*64 + nf*16 + lr;          // C col
        float v = acc[mf][nf][r];
        if (MODE == 1 && z == 0) v = v / (1.0f + expf(-v));   // silu
        if (MODE == 0) {
          C[(size_t)(gc >> 7) * ((size_t)TS * DH) + (size_t)gr * DH + (gc & 127)] = v;
        } else {
          C[(size_t)gr * ldc + gc] = v;
        }
      }
}

// ---------------------------------------------------------------------------
// Tiled fp32 GEMM (attention QK^T only now).  TB=1: B (N,K), A@B^T.
// ---------------------------------------------------------------------------
template<int TB, int EPI>
__global__ __launch_bounds__(256) void gemm_k(
    const float* __restrict__ A, const float* __restrict__ B,
    float* __restrict__ C,
    int M, int N, int K, int lda, int ldb, int ldc,
    long sA, long sB, long sC) {
  const int z = blockIdx.z;
  A += (size_t)z * sA; B += (size_t)z * sB; C += (size_t)z * sC;
  const int n0 = blockIdx.x * 128, m0 = blockIdx.y * 128;
  const int tid = threadIdx.x;
  const int tr = tid >> 4, tc = tid & 15;
  __shared__ float As[16][132];
  __shared__ float Bs[16][132];
  float acc[8][8];
  #pragma unroll
  for (int i = 0; i < 8; ++i)
    #pragma unroll
    for (int j = 0; j < 8; ++j) acc[i][j] = 0.f;

  for (int k0 = 0; k0 < K; k0 += 16) {
    #pragma unroll
    for (int l = 0; l < 2; ++l) {
      int fi = tid + l * 256;
      int row = fi >> 2, kq = fi & 3;
      float4 av = *(const float4*)&A[(size_t)(m0 + row) * lda + k0 + kq * 4];
      As[kq*4+0][row] = av.x; As[kq*4+1][row] = av.y;
      As[kq*4+2][row] = av.z; As[kq*4+3][row] = av.w;
    }
    if (TB == 0) {
      #pragma unroll
      for (int l = 0; l < 2; ++l) {
        int fi = tid + l * 256;
        int kr = fi >> 5, cq = fi & 31;
        int gc = n0 + cq * 4;
        float4 bv = make_float4(0.f, 0.f, 0.f, 0.f);
        if (gc < N) bv = *(const float4*)&B[(size_t)(k0 + kr) * ldb + gc];
        *(float4*)&Bs[kr][cq * 4] = bv;
      }
    } else {
      #pragma unroll
      for (int l = 0; l < 2; ++l) {
        int fi = tid + l * 256;
        int col = fi >> 2, kq = fi & 3;
        int gc = n0 + col;
        float4 bv = make_float4(0.f, 0.f, 0.f, 0.f);
        if (gc < N) bv = *(const float4*)&B[(size_t)gc * ldb + k0 + kq * 4];
        Bs[kq*4+0][col] = bv.x; Bs[kq*4+1][col] = bv.y;
        Bs[kq*4+2][col] = bv.z; Bs[kq*4+3][col] = bv.w;
      }
    }
    __syncthreads();
    #pragma unroll
    for (int kk = 0; kk < 16; ++kk) {
      float a[8], b[8];
      *(float4*)&a[0] = *(const float4*)&As[kk][tr * 8];
      *(float4*)&a[4] = *(const float4*)&As[kk][tr * 8 + 4];
      *(float4*)&b[0] = *(const float4*)&Bs[kk][tc * 4];
      *(float4*)&b[4] = *(const float4*)&Bs[kk][64 + tc * 4];
      #pragma unroll
      for (int i = 0; i < 8; ++i)
        #pragma unroll
        for (int j = 0; j < 8; ++j)
          acc[i][j] = fmaf(a[i], b[j], acc[i][j]);
    }
    __syncthreads();
  }

  #pragma unroll
  for (int i = 0; i < 8; ++i) {
    int gr = m0 + tr * 8 + i;
    #pragma unroll
    for (int half = 0; half < 2; ++half) {
      int gc = n0 + half * 64 + tc * 4;
      if (gc < N)
        *(float4*)&C[(size_t)gr * ldc + gc] =
            make_float4(acc[i][half*4], acc[i][half*4+1],
                        acc[i][half*4+2], acc[i][half*4+3]);
    }
  }
}

// ---------------------------------------------------------------------------
// Split-K fp32 GEMM partial (dwh / ddv / PV)
// ---------------------------------------------------------------------------
template<int AMUL>
__global__ __launch_bounds__(256) void gemm_splitk(
    const float* __restrict__ A, const float* __restrict__ A2,
    const float* __restrict__ B, float* __restrict__ P,
    int M, int N, int Kps, int lda, int ldb, int ldc,
    long sAb, long sBb, long cColb, long sCsp, int NS) {
  const int bt = blockIdx.z / NS, sp = blockIdx.z % NS;
  A += (size_t)bt * sAb + (size_t)sp * Kps;
  if (AMUL) A2 += (size_t)bt * sAb + (size_t)sp * Kps;
  B += (size_t)bt * sBb + (size_t)sp * Kps * ldb;
  P += (size_t)sp * sCsp + (size_t)bt * cColb;
  const int n0 = blockIdx.x * 128, m0 = blockIdx.y * 128;
  const int tid = threadIdx.x;
  const int tr = tid >> 4, tc = tid & 15;
  __shared__ float As[16][132];
  __shared__ float Bs[16][132];
  float acc[8][8];
  #pragma unroll
  for (int i = 0; i < 8; ++i)
    #pragma unroll
    for (int j = 0; j < 8; ++j) acc[i][j] = 0.f;

  for (int k0 = 0; k0 < Kps; k0 += 16) {
    #pragma unroll
    for (int l = 0; l < 2; ++l) {
      int fi = tid + l * 256;
      int row = fi >> 2, kq = fi & 3;
      size_t ai = (size_t)(m0 + row) * lda + k0 + kq * 4;
      float4 av = *(const float4*)&A[ai];
      if (AMUL) {
        float4 a2 = *(const float4*)&A2[ai];
        av.x *= a2.x; av.y *= a2.y; av.z *= a2.z; av.w *= a2.w;
      }
      As[kq*4+0][row] = av.x; As[kq*4+1][row] = av.y;
      As[kq*4+2][row] = av.z; As[kq*4+3][row] = av.w;
    }
    #pragma unroll
    for (int l = 0; l < 2; ++l) {
      int fi = tid + l * 256;
      int kr = fi >> 5, cq = fi & 31;
      int gc = n0 + cq * 4;
      float4 bv = make_float4(0.f, 0.f, 0.f, 0.f);
      if (gc < N) bv = *(const float4*)&B[(size_t)(k0 + kr) * ldb + gc];
      *(float4*)&Bs[kr][cq * 4] = bv;
    }
    __syncthreads();
    #pragma unroll
    for (int kk = 0; kk < 16; ++kk) {
      float a[8], b[8];
      *(float4*)&a[0] = *(const float4*)&As[kk][tr * 8];
      *(float4*)&a[4] = *(const float4*)&As[kk][tr * 8 + 4];
      *(float4*)&b[0] = *(const float4*)&Bs[kk][tc * 4];
      *(float4*)&b[4] = *(const float4*)&Bs[kk][64 + tc * 4];
      #pragma unroll
      for (int i = 0; i < 8; ++i)
        #pragma unroll
        for (int j = 0; j < 8; ++j)
          acc[i][j] = fmaf(a[i], b[j], acc[i][j]);
    }
    __syncthreads();
  }

  #pragma unroll
  for (int i = 0; i < 8; ++i) {
    int gr = m0 + tr * 8 + i;
    #pragma unroll
    for (int half = 0; half < 2; ++half) {
      int gc = n0 + half * 64 + tc * 4;
      if (gc < N)
        *(float4*)&P[(size_t)gr * ldc + gc] =
            make_float4(acc[i][half*4], acc[i][half*4+1],
                        acc[i][half*4+2], acc[i][half*4+3]);
    }
  }
}

// ---------------------------------------------------------------------------
// reduce NS split partials (float4), apply epilogue.
// EPI: 0 none, 1 gelu(exact), 2 tanh, 3 add residual R
// ---------------------------------------------------------------------------
template<int EPI>
__global__ __launch_bounds__(256) void reduce_k(const float* __restrict__ P,
                                                const float* __restrict__ R,
                                                float* __restrict__ out,
                                                long n4, long sSp4, int NS) {
  long i = (long)blockIdx.x * 256 + threadIdx.x;
  const long stride = (long)gridDim.x * 256;
  for (; i < n4; i += stride) {
    float4 s = ((const float4*)P)[i];
    for (int sp = 1; sp < NS; ++sp) {
      float4 v = ((const float4*)P)[i + sp * sSp4];
      s.x += v.x; s.y += v.y; s.z += v.z; s.w += v.w;
    }
    if (EPI == 1) {
      s.x = 0.5f*s.x*(1.0f+erff(s.x*0.70710678118654752f));
      s.y = 0.5f*s.y*(1.0f+erff(s.y*0.70710678118654752f));
      s.z = 0.5f*s.z*(1.0f+erff(s.z*0.70710678118654752f));
      s.w = 0.5f*s.w*(1.0f+erff(s.w*0.70710678118654752f));
    } else if (EPI == 2) {
      s.x = tanhf(s.x); s.y = tanhf(s.y); s.z = tanhf(s.z); s.w = tanhf(s.w);
    } else if (EPI == 3) {
      float4 rv = ((const float4*)R)[i];
      s.x += rv.x; s.y += rv.y; s.z += rv.z; s.w += rv.w;
    }
    ((float4*)out)[i] = s;
  }
}

// ---------------------------------------------------------------------------
// Per-(head, t) on PACKED qkv (48, T, DH): rmsnorm(q), rmsnorm(k), RoPE both,
// scale q by Dh^-0.5.  In place.  Head n: q at plane n, k at plane NH+n.
// ---------------------------------------------------------------------------
__global__ __launch_bounds__(64) void qkrope_k(float* __restrict__ qkvp,
                                               const float* __restrict__ qnw,
                                               const float* __restrict__ knw) {
  const int n = blockIdx.x, t = blockIdx.y, i = threadIdx.x;
  float* qr = qkvp + ((size_t)n * TS + t) * DH;
  float* kr = qkvp + ((size_t)(NH + n) * TS + t) * DH;
  float q1 = qr[i], q2 = qr[i + 64];
  float k1 = kr[i], k2 = kr[i + 64];
  float ssq = q1 * q1 + q2 * q2;
  float ssk = k1 * k1 + k2 * k2;
  #pragma unroll
  for (int d = 1; d < 64; d <<= 1) {
    ssq += __shfl_xor(ssq, d);
    ssk += __shfl_xor(ssk, d);
  }
  const float rq = rsqrtf(ssq * (1.0f / DH) + 1e-6f);
  const float rk = rsqrtf(ssk * (1.0f / DH) + 1e-6f);
  float qn1 = q1 * rq * qnw[i], qn2 = q2 * rq * qnw[i + 64];
  float kn1 = k1 * rk * knw[i], kn2 = k2 * rk * knw[i + 64];
  float inv = 1.0f / powf(10000.0f, (float)i * (1.0f / 64.0f));
  float ang = (float)t * inv;
  float c = (float)cos((double)ang);
  float s = (float)sin((double)ang);
  const float scale = 0.08838834764831845f;  // 128^-0.5 (q only)
  qr[i]      = (qn1 * c - qn2 * s) * scale;
  qr[i + 64] = (qn2 * c + qn1 * s) * scale;
  kr[i]      = kn1 * c - kn2 * s;
  kr[i + 64] = kn2 * c + kn1 * s;
}

// ---------------------------------------------------------------------------
// dyn-w: w[t,c,i,n] = sum_kk dwh[t,c,kk]*qkw[c,kk,i,n]; rmsnorm_noscale over
// n (16) for i<2.
// ---------------------------------------------------------------------------
__global__ __launch_bounds__(256) void dynw_k(const float* __restrict__ dwh,
                                              const float* __restrict__ qkw,
                                              float* __restrict__ dynw) {
  const int t = blockIdx.x, tid = threadIdx.x;
  __shared__ float dwhs[256];
  dwhs[tid] = dwh[(size_t)t * 256 + tid];
  __syncthreads();
  const int c = tid >> 6, r = tid & 63, ifull = r >> 4, n = r & 15;
  const float* qp = qkw + (size_t)(c * 64) * 64 + ifull * 16 + n;
  const float* dp = dwhs + c * 64;
  float acc = 0.f;
  #pragma unroll 8
  for (int kk = 0; kk < 64; ++kk) acc = fmaf(dp[kk], qp[(size_t)kk * 64], acc);
  float ss = acc * acc;
  #pragma unroll
  for (int m = 1; m < 16; m <<= 1) ss += __shfl_xor(ss, m);
  float v = (ifull < 2) ? acc * rsqrtf(ss * (1.0f / 16) + 1e-6f) : acc;
  dynw[(size_t)t * 256 + tid] = v;
}

// ---------------------------------------------------------------------------
// cross_head_proj, in place on a logits CHUNK x (NH, TTCH, TS).
// ---------------------------------------------------------------------------
__global__ __launch_bounds__(256) void chp_k(float* __restrict__ x,
                                             const float* __restrict__ dynw,
                                             const float* __restrict__ ddv,
                                             int cq, int ck, int oq, int ok,
                                             int t0) {
  const int tl = blockIdx.y;
  const int tg = t0 + tl;
  const int s = blockIdx.x * 256 + threadIdx.x;
  const int tid = threadIdx.x;
  __shared__ float qw[64];
  __shared__ float qdds[16];
  if (tid < 64) qw[tid] = dynw[(size_t)tg * 256 + cq * 64 + tid];
  else if (tid < 80) qdds[tid - 64] = ddv[(size_t)tg * 64 + oq + (tid - 64)];
  __syncthreads();
  const size_t plane = (size_t)TTCH * TS;
  float* p = x + (size_t)tl * TS + s;
  float xv[16];
  #pragma unroll
  for (int n = 0; n < 16; ++n) xv[n] = p[n * plane];
  float qh0 = 0.f, qh1 = 0.f, kh0 = 0.f, kh1 = 0.f;
  const float* kwp = dynw + (size_t)s * 256 + ck * 64;
  #pragma unroll
  for (int n = 0; n < 16; ++n) {
    qh0 = fmaf(xv[n], qw[n], qh0);
    qh1 = fmaf(xv[n], qw[16 + n], qh1);
    kh0 = fmaf(xv[n], kwp[n], kh0);
    kh1 = fmaf(xv[n], kwp[16 + n], kh1);
  }
  const float* kddp = ddv + (size_t)s * 64 + ok;
  #pragma unroll
  for (int n = 0; n < 16; ++n) {
    float r = xv[n]
            + qh0 * qw[32 + n] + qh1 * qw[48 + n]
            + kh0 * kwp[32 + n] + kh1 * kwp[48 + n]
            + xv[n] * (qdds[n] + kddp[n]);
    p[n * plane] = r;
  }
}

// ---------------------------------------------------------------------------
// causal softmax in place on chunk (NH, TTCH, TS).
// ---------------------------------------------------------------------------
__global__ __launch_bounds__(256) void softmax_k(float* __restrict__ x, int t0) {
  const int tl = blockIdx.x, n = blockIdx.y, tid = threadIdx.x;
  const int tg = t0 + tl;
  float* row = x + ((size_t)n * TTCH + tl) * TS;
  float l[8];
  float m = -INFINITY;
  #pragma unroll
  for (int k = 0; k < 8; ++k) {
    int s = tid + k * 256;
    l[k] = (s <= tg) ? row[s] : -INFINITY;
    m = fmaxf(m, l[k]);
  }
  #pragma unroll
  for (int d = 1; d < 64; d <<= 1) m = fmaxf(m, __shfl_xor(m, d));
  __shared__ float red[4];
  if ((tid & 63) == 0) red[tid >> 6] = m;
  __syncthreads();
  m = fmaxf(fmaxf(red[0], red[1]), fmaxf(red[2], red[3]));
  float sum = 0.f;
  #pragma unroll
  for (int k = 0; k < 8; ++k) {
    int s = tid + k * 256;
    l[k] = (s <= tg) ? expf(l[k] - m) : 0.f;
    sum += l[k];
  }
  #pragma unroll
  for (int d = 1; d < 64; d <<= 1) sum += __shfl_xor(sum, d);
  __syncthreads();
  if ((tid & 63) == 0) red[tid >> 6] = sum;
  __syncthreads();
  sum = red[0] + red[1] + red[2] + red[3];
  const float isum = 1.0f / sum;
  #pragma unroll
  for (int k = 0; k < 8; ++k) row[tid + k * 256] = l[k] * isum;
}

// ---------------------------------------------------------------------------
extern "C" void kernel_launch(void* const* d_in, const int* in_sizes, int n_in,
                              void* d_out, int out_size, void* d_ws, size_t ws_size,
                              hipStream_t stream) {
  (void)in_sizes; (void)n_in; (void)out_size; (void)ws_size;
  const float* x    = (const float*)d_in[0];
  const float* anw  = (const float*)d_in[1];
  const float* wqkv = (const float*)d_in[2];
  const float* qnw  = (const float*)d_in[3];
  const float* knw  = (const float*)d_in[4];
  const float* dw1  = (const float*)d_in[5];
  const float* qkw  = (const float*)d_in[6];
  const float* dd   = (const float*)d_in[7];
  const float* wo   = (const float*)d_in[8];
  const float* fnw  = (const float*)d_in[9];
  const float* w1f  = (const float*)d_in[10];
  const float* w3f  = (const float*)d_in[11];
  const float* w2f  = (const float*)d_in[12];
  float* out = (float*)d_out;
  float* ws = (float*)d_ws;

  // Workspace layout (floats). High-water 26,345,472 floats = 105.4 MB
  // (identical to the round-5/6 proven footprint).
  const size_t SZ_D2 = (size_t)TS * DM;            // 4,194,304
  const size_t SZ_H  = (size_t)TS * DH;            // 262,144 per head
  float* hn    = ws;                               // [0, 4.19M)
  float* qkvp  = hn + SZ_D2;                       // [4.19M, 16.78M) packed (48,T,128)
  float* dwh   = qkvp + (size_t)TS * 3 * DM;       // 0.52M
  float* dynw  = dwh + (size_t)TS * 256;           // 0.52M
  float* ddv   = dynw + (size_t)TS * 256;          // 0.13M
  float* logc  = ddv + (size_t)TS * 64;            // [17.96M, 26.35M)
  float* qb    = qkvp;
  float* kb    = qkvp + NH * SZ_H;
  float* vb    = qkvp + 2 * NH * SZ_H;
  // Phase B aliases:
  float* ob    = hn;                               // (T,D) [hn dead]
  float* pwo   = dwh;                              // wo partials 2x4.19M
  float* hb    = qkvp;                             // (T,D) [qkv dead]
  float* fnb   = hn;                               // (T,D) [ob dead after wo]
  float* g1c   = qkvp + SZ_D2;                     // [8.39M, 14.16M) (FCHG,FF)
  float* g3c   = g1c + (size_t)FCHG * FF;          // [14.16M, 19.92M)
  float* pw2   = g3c + (size_t)FCHG * FF;          // [19.92M, 24.12M) 2x(FCHG,DM)
  float* part  = out;                              // small split-K partials

  const long sLG = (long)TTCH * TS;

  // 1. hn = rmsnorm(x, attn_norm_w)
  rmsnorm_k<<<TS, 256, 0, stream>>>(x, anw, hn);
  // 2. qkv = hn @ wqkv  (MFMA bf16x3, packed-head write)
  mfgemm<0><<<dim3(48, 16, 1), 256, 0, stream>>>(hn, nullptr, wqkv, nullptr,
      qkvp, TS, 3*DM, DM, DM, 3*DM, 0, 0);
  // 3. dyn-w pieces (fp32 split-K, partials in d_out)
  gemm_splitk<0><<<dim3(2, 16, 8), 256, 0, stream>>>(hn, nullptr, dw1, part,
      TS, 256, 256, DM, 256, 256, 0, 0, 0, (long)TS * 256, 8);
  reduce_k<1><<<512, 256, 0, stream>>>(part, nullptr, dwh,
      (long)TS * 256 / 4, (long)TS * 256 / 4, 8);          // gelu
  gemm_splitk<0><<<dim3(1, 16, 8), 256, 0, stream>>>(hn, nullptr, dd, part,
      TS, 64, 256, DM, 64, 64, 0, 0, 0, (long)TS * 64, 8);
  reduce_k<2><<<128, 256, 0, stream>>>(part, nullptr, ddv,
      (long)TS * 64 / 4, (long)TS * 64 / 4, 8);            // tanh
  dynw_k<<<TS, 256, 0, stream>>>(dwh, qkw, dynw);
  // 4. q/k: rmsnorm + rope + q-scale, in place on packed layout
  qkrope_k<<<dim3(NH, TS), 64, 0, stream>>>(qkvp, qnw, knw);
  // 5-9. attention in query chunks of TTCH rows (fp32 path, unchanged)
  for (int t0 = 0; t0 < TS; t0 += TTCH) {
    gemm_k<1,0><<<dim3(16, TTCH/128, NH), 256, 0, stream>>>(
        qb + (size_t)t0 * DH, kb, logc,
        TTCH, TS, DH, DH, DH, TS, (long)SZ_H, (long)SZ_H, sLG);
    chp_k<<<dim3(8, TTCH), 256, 0, stream>>>(logc, dynw, ddv, 0, 1, 0, 16, t0);
    softmax_k<<<dim3(TTCH, NH), 256, 0, stream>>>(logc, t0);
    chp_k<<<dim3(8, TTCH), 256, 0, stream>>>(logc, dynw, ddv, 2, 3, 32, 48, t0);
    gemm_splitk<0><<<dim3(1, TTCH/128, NH * 8), 256, 0, stream>>>(
        logc, nullptr, vb, part, TTCH, DH, TS / 8, TS, DH, DM,
        sLG, (long)SZ_H, (long)DH, (long)TTCH * DM, 8);
    reduce_k<0><<<512, 256, 0, stream>>>(part, nullptr, ob + (size_t)t0 * DM,
        (long)TTCH * DM / 4, (long)TTCH * DM / 4, 8);
  }
  // 10. h = x + o @ wo  (MFMA bf16x3 split-K 2; residual in reduce)
  mfgemm<3><<<dim3(16, 16, 2), 256, 0, stream>>>(ob, nullptr, wo, nullptr,
      pwo, TS, DM, DM / 2, DM, DM, DM, (long)TS * DM);
  reduce_k<3><<<2048, 256, 0, stream>>>(pwo, x, hb,
      (long)TS * DM / 4, (long)TS * DM / 4, 2);
  // 11. fn = rmsnorm(h, ffn_norm_w)
  rmsnorm_k<<<TS, 256, 0, stream>>>(hb, fnw, fnb);
  // 12-13. FFN per 1024-row chunk (MFMA bf16x3):
  //   dual-B: g1 = silu(fn@w1f), g3 = fn@w3f; then (g1*g3)@w2f split-K 2
  //   with the elementwise product fused into the A staging; residual in reduce.
  for (int r0 = 0; r0 < TS; r0 += FCHG) {
    mfgemm<1><<<dim3(44, FCHG/128, 2), 256, 0, stream>>>(
        fnb + (size_t)r0 * DM, nullptr, w1f, w3f, g1c,
        FCHG, FF, DM, DM, FF, FF, (long)FCHG * FF);
    mfgemm<2><<<dim3(16, FCHG/128, 2), 256, 0, stream>>>(
        g1c, g3c, w2f, nullptr, pw2,
        FCHG, DM, FF / 2, FF, DM, DM, (long)FCHG * DM);
    reduce_k<3><<<1024, 256, 0, stream>>>(pw2, hb + (size_t)r0 * DM,
        out + (size_t)r0 * DM,
        (long)FCHG * DM / 4, (long)FCHG * DM / 4, 2);
  }
}